// Round 1
// baseline (190.494 us; speedup 1.0000x reference)
//
#include <hip/hip_runtime.h>
#include <hip/hip_bf16.h>
#include <stdint.h>

namespace gat {
constexpr int NB   = 16;
constexpr int NN   = 512;
constexpr int FIN  = 256;
constexpr int FOUT = 256;
constexpr int H    = 8;
constexpr int NE   = 50;
constexpr int TI   = 16;    // i-tile rows per block (attn)
constexpr int TJ   = 64;    // j-tile
constexpr int PIS  = 72;    // P i-stride in bf16 elems (64 + 8 pad)
constexpr int PHS  = 1160;  // P h-stride in bf16 elems (16*72 + 8 -> 4-bank stagger per h)
}
using namespace gat;

__device__ __forceinline__ float bf_lo(unsigned u) { return __uint_as_float(u << 16); }
__device__ __forceinline__ float bf_hi(unsigned u) { return __uint_as_float(u & 0xffff0000u); }

// ---------------- Kernel A: Wh = x @ W ; s1 = Wh.a1 ; s2 = Wh.a2 ----------------
// grid 512 (16 rows each), block 256. Wave ig owns rows ig*4..ig*4+3, lane fq owns f-quad fq*4.
__global__ __launch_bounds__(256, 2) void k_gemm(
    const float* __restrict__ x, const float* __restrict__ Wm,
    const float* __restrict__ a1, const float* __restrict__ a2,
    float* __restrict__ Wh, float* __restrict__ s1, float* __restrict__ s2)
{
  __shared__ float xS[16 * 256];
  const int t    = threadIdx.x;
  const int row0 = blockIdx.x * 16;

  { // stage 16 rows of x (16 KB)
    const float4* xg = (const float4*)(x + (size_t)row0 * FIN);
    float4* xs = (float4*)xS;
    #pragma unroll
    for (int v = 0; v < 4; ++v) xs[t + v * 256] = xg[t + v * 256];
  }
  __syncthreads();

  const int ig = t >> 6;       // wave 0..3
  const int fq = t & 63;       // f-quad 0..63
  const int f0 = fq * 4;

  float acc[4][4] = {{0.f,0.f,0.f,0.f},{0.f,0.f,0.f,0.f},{0.f,0.f,0.f,0.f},{0.f,0.f,0.f,0.f}};

  #pragma unroll 4
  for (int k4 = 0; k4 < 64; ++k4) {
    const int k = k4 * 4;
    const float4 w0 = *(const float4*)(Wm + (k + 0) * FOUT + f0);
    const float4 w1 = *(const float4*)(Wm + (k + 1) * FOUT + f0);
    const float4 w2 = *(const float4*)(Wm + (k + 2) * FOUT + f0);
    const float4 w3 = *(const float4*)(Wm + (k + 3) * FOUT + f0);
    #pragma unroll
    for (int r = 0; r < 4; ++r) {
      const float4 xv = *(const float4*)(xS + (ig * 4 + r) * 256 + k); // wave-uniform broadcast
      acc[r][0] += xv.x * w0.x + xv.y * w1.x + xv.z * w2.x + xv.w * w3.x;
      acc[r][1] += xv.x * w0.y + xv.y * w1.y + xv.z * w2.y + xv.w * w3.y;
      acc[r][2] += xv.x * w0.z + xv.y * w1.z + xv.z * w2.z + xv.w * w3.z;
      acc[r][3] += xv.x * w0.w + xv.y * w1.w + xv.z * w2.w + xv.w * w3.w;
    }
  }

  // store Wh (fp32)
  #pragma unroll
  for (int r = 0; r < 4; ++r) {
    const int row = row0 + ig * 4 + r;
    float4 o; o.x = acc[r][0]; o.y = acc[r][1]; o.z = acc[r][2]; o.w = acc[r][3];
    *(float4*)(Wh + (size_t)row * FOUT + f0) = o;
  }

  // s1/s2: per (row, h) dot over d=32, spread across 8 lanes (fq&7), xor-reduce
  const int d0 = (fq & 7) * 4;
  const int h  = fq >> 3;
  const float4 a1v = *(const float4*)(a1 + d0);
  const float4 a2v = *(const float4*)(a2 + d0);
  #pragma unroll
  for (int r = 0; r < 4; ++r) {
    float p1 = acc[r][0]*a1v.x + acc[r][1]*a1v.y + acc[r][2]*a1v.z + acc[r][3]*a1v.w;
    float p2 = acc[r][0]*a2v.x + acc[r][1]*a2v.y + acc[r][2]*a2v.z + acc[r][3]*a2v.w;
    p1 += __shfl_xor(p1, 1); p2 += __shfl_xor(p2, 1);
    p1 += __shfl_xor(p1, 2); p2 += __shfl_xor(p2, 2);
    p1 += __shfl_xor(p1, 4); p2 += __shfl_xor(p2, 4);
    if ((fq & 7) == 0) {
      const int row = row0 + ig * 4 + r;
      s1[row * H + h] = p1;
      s2[row * H + h] = p2;
    }
  }
}

// ---------------- Kernel B: attention + softmax + aggregate + LN + ELU ----------------
// grid = NB * (NN/TI) = 512 blocks, block 256.
// e-phase:  wave w, lane jj; i-set {w, w+4, w+8, w+12}; no max-subtraction (mask = -80).
// agg:      wave w owns feature quarter [w*64, w*64+64), lane covers (f-quad, i-sub).
__global__ __launch_bounds__(256, 2) void k_attn(
    const int* __restrict__ adj, const int* __restrict__ ety,
    const float* __restrict__ s1, const float* __restrict__ s2,
    const float* __restrict__ Wh, const float* __restrict__ emb,
    const float* __restrict__ gam, const float* __restrict__ bet,
    float* __restrict__ out)
{
  __shared__ alignas(16) unsigned char smemP[2 * 8 * PHS];  // 18560 B: P bf16, later hS fp32
  __shared__ float embS[8 * NE];                            // transposed [h][et] for bank spread
  __shared__ float lS[16 * 8];

  __hip_bfloat16* Pb = (__hip_bfloat16*)smemP;
  float* hS = (float*)smemP;   // [16][260] overlay, used after P is dead

  const int t    = threadIdx.x;
  const int b    = blockIdx.x >> 5;
  const int i0   = (blockIdx.x & 31) * TI;
  const int w    = t >> 6;
  const int lan  = t & 63;
  const int jj   = lan;                 // e-phase lane role
  const int fq   = w * 16 + (lan & 15); // agg lane role: f-quad
  const int f0   = fq * 4;
  const int h    = fq >> 3;
  const int isub = lan >> 4;            // 0..3

  for (int v = t; v < NE * H; v += 256) {
    const int e = v >> 3, hh = v & 7;
    embS[hh * NE + e] = emb[v];
  }

  // preload s1 for this wave's i-set (invariant over j-tiles)
  float s1r[4][8];
  #pragma unroll
  for (int r = 0; r < 4; ++r) {
    const float* p = s1 + ((size_t)(b * NN) + i0 + w + 4 * r) * H;
    const float4 ua = *(const float4*)p;
    const float4 ub = *(const float4*)(p + 4);
    s1r[r][0]=ua.x; s1r[r][1]=ua.y; s1r[r][2]=ua.z; s1r[r][3]=ua.w;
    s1r[r][4]=ub.x; s1r[r][5]=ub.y; s1r[r][6]=ub.z; s1r[r][7]=ub.w;
  }

  float acc[4][4]   = {{0.f,0.f,0.f,0.f},{0.f,0.f,0.f,0.f},{0.f,0.f,0.f,0.f},{0.f,0.f,0.f,0.f}};
  float lpart[4][8] = {};
  __syncthreads();

  #pragma unroll 1
  for (int tj = 0; tj < NN / TJ; ++tj) {
    const int j0 = tj * TJ;
    // ---- e phase: P[h][i][jj] = exp(e), lpart += exp(e) ----
    {
      const float* p2 = s2 + ((size_t)(b * NN) + j0 + jj) * H;
      const float4 ua = *(const float4*)p2;
      const float4 ub = *(const float4*)(p2 + 4);
      const float s2v[8] = {ua.x,ua.y,ua.z,ua.w,ub.x,ub.y,ub.z,ub.w};
      #pragma unroll
      for (int r = 0; r < 4; ++r) {
        const int i = w + 4 * r;
        const int base = ((b * NN) + (i0 + i)) * NN + j0 + jj;
        const int av = adj[base];
        const int ev = ety[base];
        #pragma unroll
        for (int hh = 0; hh < 8; ++hh) {
          float e = s1r[r][hh] + s2v[hh] + embS[hh * NE + ev];
          e = (e > 0.f) ? e : 0.2f * e;       // leaky_relu(0.2)
          e = av ? e : -80.f;                  // mask (exp(-80)~2e-35: matches -1e9 semantics incl. all-masked rows)
          const float pz = __expf(e);
          lpart[r][hh] += pz;
          Pb[hh * PHS + i * PIS + jj] = __float2bfloat16(pz);
        }
      }
    }
    __syncthreads();
    // ---- aggregation: acc[i][f] += P[h][i][j] * Wh[j][f]  (wave owns f-quarter) ----
    #pragma unroll 2
    for (int c = 0; c < 8; ++c) {
      const int jc = c * 8;
      float4 whv[8];
      #pragma unroll
      for (int q = 0; q < 8; ++q)
        whv[q] = *(const float4*)(Wh + ((size_t)(b * NN) + j0 + jc + q) * FOUT + f0);
      #pragma unroll
      for (int r = 0; r < 4; ++r) {
        const int i = isub + 4 * r;
        const uint4 pr = *(const uint4*)(smemP + 2 * (h * PHS + i * PIS + jc));
        const float pv[8] = { bf_lo(pr.x), bf_hi(pr.x), bf_lo(pr.y), bf_hi(pr.y),
                              bf_lo(pr.z), bf_hi(pr.z), bf_lo(pr.w), bf_hi(pr.w) };
        #pragma unroll
        for (int q = 0; q < 8; ++q) {
          acc[r][0] += pv[q] * whv[q].x;
          acc[r][1] += pv[q] * whv[q].y;
          acc[r][2] += pv[q] * whv[q].z;
          acc[r][3] += pv[q] * whv[q].w;
        }
      }
    }
    __syncthreads();
  }

  // ---- softmax denominator: butterfly over 64 lanes, publish via lS ----
  #pragma unroll
  for (int r = 0; r < 4; ++r) {
    #pragma unroll
    for (int hh = 0; hh < 8; ++hh) {
      float v = lpart[r][hh];
      v += __shfl_xor(v, 1);  v += __shfl_xor(v, 2);  v += __shfl_xor(v, 4);
      v += __shfl_xor(v, 8);  v += __shfl_xor(v, 16); v += __shfl_xor(v, 32);
      lpart[r][hh] = v;
    }
  }
  if (lan == 0) {
    #pragma unroll
    for (int r = 0; r < 4; ++r)
      #pragma unroll
      for (int hh = 0; hh < 8; ++hh)
        lS[(w + 4 * r) * 8 + hh] = lpart[r][hh];
  }
  __syncthreads();

  // ---- normalize, stash h into LDS (P buffer is dead) ----
  #pragma unroll
  for (int r = 0; r < 4; ++r) {
    const int i = isub + 4 * r;
    const float linv = 1.0f / lS[i * 8 + h];
    float4 hv;
    hv.x = acc[r][0] * linv; hv.y = acc[r][1] * linv;
    hv.z = acc[r][2] * linv; hv.w = acc[r][3] * linv;
    *(float4*)(hS + i * 260 + f0) = hv;
  }
  __syncthreads();

  // ---- LayerNorm + ELU + store: wave w handles i in {w, w+4, ...}, lane covers f = lan*4 ----
  const float4 g4 = *(const float4*)(gam + lan * 4);
  const float4 b4 = *(const float4*)(bet + lan * 4);
  #pragma unroll
  for (int r = 0; r < 4; ++r) {
    const int i = w + 4 * r;
    const float4 v = *(const float4*)(hS + i * 260 + lan * 4);
    float sum = v.x + v.y + v.z + v.w;
    float ssq = v.x*v.x + v.y*v.y + v.z*v.z + v.w*v.w;
    #pragma unroll
    for (int s = 1; s < 64; s <<= 1) { sum += __shfl_xor(sum, s); ssq += __shfl_xor(ssq, s); }
    const float mu  = sum * (1.0f / 256.0f);
    const float var = ssq * (1.0f / 256.0f) - mu * mu;
    const float rst = rsqrtf(var + 1e-5f);
    float4 o;
    o.x = (v.x - mu) * rst * g4.x + b4.x;
    o.y = (v.y - mu) * rst * g4.y + b4.y;
    o.z = (v.z - mu) * rst * g4.z + b4.z;
    o.w = (v.w - mu) * rst * g4.w + b4.w;
    o.x = o.x > 0.f ? o.x : __expf(o.x) - 1.f;
    o.y = o.y > 0.f ? o.y : __expf(o.y) - 1.f;
    o.z = o.z > 0.f ? o.z : __expf(o.z) - 1.f;
    o.w = o.w > 0.f ? o.w : __expf(o.w) - 1.f;
    *(float4*)(out + ((size_t)(b * NN) + i0 + i) * FOUT + lan * 4) = o;
  }
}

extern "C" void kernel_launch(void* const* d_in, const int* in_sizes, int n_in,
                              void* d_out, int out_size, void* d_ws, size_t ws_size,
                              hipStream_t stream) {
  (void)in_sizes; (void)n_in; (void)out_size; (void)ws_size;
  const float* x   = (const float*)d_in[0];
  const int*   adj = (const int*)  d_in[1];
  const int*   ety = (const int*)  d_in[2];
  const float* Wm  = (const float*)d_in[3];
  const float* a1  = (const float*)d_in[4];
  const float* a2  = (const float*)d_in[5];
  const float* emb = (const float*)d_in[6];
  const float* gam = (const float*)d_in[7];
  const float* bet = (const float*)d_in[8];
  float* out = (float*)d_out;

  float* Wh = (float*)d_ws;                         // 8192*256 fp32 = 8 MB
  float* s1 = Wh + (size_t)NB * NN * FOUT;          // 8192*8
  float* s2 = s1 + (size_t)NB * NN * H;             // 8192*8

  k_gemm<<<dim3(NB * NN / 16), dim3(256), 0, stream>>>(x, Wm, a1, a2, Wh, s1, s2);
  k_attn<<<dim3(NB * (NN / TI)), dim3(256), 0, stream>>>(adj, ety, s1, s2, Wh, emb, gam, bet, out);
}

// Round 2
// 168.379 us; speedup vs baseline: 1.1313x; 1.1313x over previous
//
#include <hip/hip_runtime.h>
#include <hip/hip_bf16.h>
#include <stdint.h>

namespace gat {
constexpr int NB   = 16;
constexpr int NN   = 512;
constexpr int FIN  = 256;
constexpr int FOUT = 256;
constexpr int H    = 8;
constexpr int NE   = 50;
constexpr float L2E  = 1.4426950408889634f;   // log2(e); s1,s2,emb pre-scaled so exp(e)=exp2(e')
constexpr float MASK = -115.41500f;           // -80 * log2e; exp2 -> 2.4e-35 (normal fp32)
}
using namespace gat;

typedef __attribute__((ext_vector_type(8))) short short8;  // 8 bf16 = 4 VGPRs (MFMA A/B frag)
typedef __attribute__((ext_vector_type(4))) float f32x4;   // MFMA C/D frag

__device__ __forceinline__ unsigned pk_bf16(unsigned ulo, unsigned uhi) {
  // inputs are float bits + 0x8000 (round-half-up); take high halves, lo in low
  return __builtin_amdgcn_perm(uhi, ulo, 0x07060302u);
}

// ---------------- Kernel A: Wh = x@W -> WhT bf16 [b][h][d][n]; s1 [row][h]; s2T [b][h][n] ----
// 512 blocks x 256. Lane map: fsel=L>>2 (16 f-quads), nq=L&3 (4 n-quads); wave ig owns f-range ig*64.
__global__ __launch_bounds__(256, 2) void k_gemm(
    const float* __restrict__ x, const float* __restrict__ Wm,
    const float* __restrict__ a1, const float* __restrict__ a2,
    unsigned short* __restrict__ WhT, float* __restrict__ s1, float* __restrict__ s2T)
{
  __shared__ float xS[16 * 256];
  const int t    = threadIdx.x;
  const int row0 = blockIdx.x * 16;

  { // stage 16 rows of x (16 KB)
    const float4* xg = (const float4*)(x + (size_t)row0 * FIN);
    float4* xs = (float4*)xS;
    #pragma unroll
    for (int v = 0; v < 4; ++v) xs[t + v * 256] = xg[t + v * 256];
  }
  __syncthreads();

  const int ig   = t >> 6;
  const int L    = t & 63;
  const int fsel = L >> 2;          // 0..15
  const int nq   = L & 3;           // 0..3
  const int f0   = ig * 64 + fsel * 4;

  float acc[4][4] = {{0.f,0.f,0.f,0.f},{0.f,0.f,0.f,0.f},{0.f,0.f,0.f,0.f},{0.f,0.f,0.f,0.f}};

  #pragma unroll 4
  for (int k4 = 0; k4 < 64; ++k4) {
    const int k = k4 * 4;
    const float4 w0 = *(const float4*)(Wm + (k + 0) * FOUT + f0);
    const float4 w1 = *(const float4*)(Wm + (k + 1) * FOUT + f0);
    const float4 w2 = *(const float4*)(Wm + (k + 2) * FOUT + f0);
    const float4 w3 = *(const float4*)(Wm + (k + 3) * FOUT + f0);
    #pragma unroll
    for (int r = 0; r < 4; ++r) {
      const float4 xv = *(const float4*)(xS + (nq * 4 + r) * 256 + k); // 4 addrs/wave, broadcast
      acc[r][0] += xv.x * w0.x + xv.y * w1.x + xv.z * w2.x + xv.w * w3.x;
      acc[r][1] += xv.x * w0.y + xv.y * w1.y + xv.z * w2.y + xv.w * w3.y;
      acc[r][2] += xv.x * w0.z + xv.y * w1.z + xv.z * w2.z + xv.w * w3.z;
      acc[r][3] += xv.x * w0.w + xv.y * w1.w + xv.z * w2.w + xv.w * w3.w;
    }
  }

  const int b  = row0 >> 9;             // batch
  const int nn = (row0 & 511) + nq * 4; // node index within batch (this lane's 4-row run)

  // WhT bf16 store: row f -> [b][f>>5][f&31][n], lane holds n-run nn..nn+3 (8 B)
  #pragma unroll
  for (int fk = 0; fk < 4; ++fk) {
    const int f = f0 + fk;
    const unsigned u0 = __float_as_uint(acc[0][fk]) + 0x8000u;
    const unsigned u1 = __float_as_uint(acc[1][fk]) + 0x8000u;
    const unsigned u2 = __float_as_uint(acc[2][fk]) + 0x8000u;
    const unsigned u3 = __float_as_uint(acc[3][fk]) + 0x8000u;
    uint2 o; o.x = pk_bf16(u0, u1); o.y = pk_bf16(u2, u3);
    *(uint2*)(WhT + (size_t)((b * 8 + (f >> 5)) * 32 + (f & 31)) * 512 + nn) = o;
  }

  // s1/s2 (pre-scaled by log2e): dot over d=32 spread across octet (fsel&7), xor-reduce 4/8/16
  const int dsub = fsel & 7;
  const int h    = f0 >> 5;
  const float4 a1v = *(const float4*)(a1 + (dsub * 4));
  const float4 a2v = *(const float4*)(a2 + (dsub * 4));
  #pragma unroll
  for (int r = 0; r < 4; ++r) {
    float p1 = acc[r][0]*a1v.x + acc[r][1]*a1v.y + acc[r][2]*a1v.z + acc[r][3]*a1v.w;
    float p2 = acc[r][0]*a2v.x + acc[r][1]*a2v.y + acc[r][2]*a2v.z + acc[r][3]*a2v.w;
    p1 += __shfl_xor(p1, 4);  p2 += __shfl_xor(p2, 4);
    p1 += __shfl_xor(p1, 8);  p2 += __shfl_xor(p2, 8);
    p1 += __shfl_xor(p1, 16); p2 += __shfl_xor(p2, 16);
    if (dsub == 0) {
      const int node = (row0 & 511) + nq * 4 + r;
      s1[(size_t)(row0 + nq * 4 + r) * H + h]    = p1 * L2E;
      s2T[(size_t)(b * 8 + h) * 512 + node]      = p2 * L2E;
    }
  }
}

// ---------------- Kernel B: e-phase -> MFMA aggregate -> softmax-norm -> LN -> ELU ----------
// 512 blocks (b x 32 i-tiles of 16) x 256 thr. Wave w owns heads {w, w+4}.
// Lane roles: i = L&15 (B-frag col / D col), quad = L>>4 (j-subchunk / D row group).
// P is computed straight into MFMA B-fragments (no LDS round-trip, no per-tile barriers).
__global__ __launch_bounds__(256, 2) void k_attn(
    const int* __restrict__ adj, const int* __restrict__ ety,
    const float* __restrict__ s1, const float* __restrict__ s2T,
    const unsigned short* __restrict__ WhT, const float* __restrict__ emb,
    const float* __restrict__ gam, const float* __restrict__ bet,
    float* __restrict__ out)
{
  __shared__ float2 embS[4 * 64];   // [wave][et] = (emb[et][w], emb[et][w+4]) * L2E
  __shared__ float2 lnS[16 * 4];    // [i][wave] partial (sum, sumsq)

  const int t    = threadIdx.x;
  const int b    = blockIdx.x >> 5;
  const int i0   = (blockIdx.x & 31) * 16;
  const int w    = t >> 6;
  const int L    = t & 63;
  const int i    = L & 15;
  const int quad = L >> 4;
  const int h0   = w, h1 = w + 4;

  { // stage emb (pair-packed per wave's 2 heads, pre-scaled)
    const int wp = t >> 6, e = t & 63;
    if (e < NE) {
      float2 v; v.x = emb[e * H + wp] * L2E; v.y = emb[e * H + wp + 4] * L2E;
      embS[t] = v;
    }
  }

  const int row = b * NN + i0 + i;           // this lane's i-row (global)
  const float si0 = s1[(size_t)row * H + h0];
  const float si1 = s1[(size_t)row * H + h1];
  const int adjBase = row * NN;
  const float* s2h0 = s2T + (size_t)(b * 8 + h0) * 512;
  const float* s2h1 = s2T + (size_t)(b * 8 + h1) * 512;
  const unsigned short* wt00 = WhT + (size_t)((b * 8 + h0) * 32 + i)      * 512; // d = i
  const unsigned short* wt01 = WhT + (size_t)((b * 8 + h0) * 32 + 16 + i) * 512; // d = 16+i
  const unsigned short* wt10 = WhT + (size_t)((b * 8 + h1) * 32 + i)      * 512;
  const unsigned short* wt11 = WhT + (size_t)((b * 8 + h1) * 32 + 16 + i) * 512;

  f32x4 acc00 = {0.f,0.f,0.f,0.f}, acc01 = {0.f,0.f,0.f,0.f};
  f32x4 acc10 = {0.f,0.f,0.f,0.f}, acc11 = {0.f,0.f,0.f,0.f};
  float l0 = 0.f, l1 = 0.f;

  __syncthreads();

  #pragma unroll 2
  for (int kc = 0; kc < 16; ++kc) {
    const int ja = kc * 32 + quad * 8;
    // ---- loads (issued up front so the scheduler can overlap with e-compute/MFMA) ----
    const int4 av0 = *(const int4*)(adj + adjBase + ja);
    const int4 av1 = *(const int4*)(adj + adjBase + ja + 4);
    const int4 ev0 = *(const int4*)(ety + adjBase + ja);
    const int4 ev1 = *(const int4*)(ety + adjBase + ja + 4);
    const float4 sa0 = *(const float4*)(s2h0 + ja);
    const float4 sb0 = *(const float4*)(s2h0 + ja + 4);
    const float4 sa1 = *(const float4*)(s2h1 + ja);
    const float4 sb1 = *(const float4*)(s2h1 + ja + 4);
    const short8 A00 = *(const short8*)(wt00 + ja);
    const short8 A01 = *(const short8*)(wt01 + ja);
    const short8 A10 = *(const short8*)(wt10 + ja);
    const short8 A11 = *(const short8*)(wt11 + ja);

    const int aq[8] = {av0.x, av0.y, av0.z, av0.w, av1.x, av1.y, av1.z, av1.w};
    const int eq[8] = {ev0.x, ev0.y, ev0.z, ev0.w, ev1.x, ev1.y, ev1.z, ev1.w};
    const float s20[8] = {sa0.x, sa0.y, sa0.z, sa0.w, sb0.x, sb0.y, sb0.z, sb0.w};
    const float s21[8] = {sa1.x, sa1.y, sa1.z, sa1.w, sb1.x, sb1.y, sb1.z, sb1.w};

    unsigned u0[8], u1[8];
    #pragma unroll
    for (int q = 0; q < 8; ++q) {
      const float2 em = embS[w * 64 + eq[q]];
      const bool on = (aq[q] != 0);
      float e0 = si0 + s20[q] + em.x;
      float e1 = si1 + s21[q] + em.y;
      e0 = fmaxf(e0, 0.2f * e0);              // leaky (scale-commutes with L2E)
      e1 = fmaxf(e1, 0.2f * e1);
      e0 = on ? e0 : MASK;
      e1 = on ? e1 : MASK;
      const float p0 = exp2f(e0);             // v_exp_f32
      const float p1 = exp2f(e1);
      l0 += p0; l1 += p1;
      u0[q] = __float_as_uint(p0) + 0x8000u;  // round-half-up bf16 prep
      u1[q] = __float_as_uint(p1) + 0x8000u;
    }
    uint4 U0, U1;
    U0.x = pk_bf16(u0[0], u0[1]); U0.y = pk_bf16(u0[2], u0[3]);
    U0.z = pk_bf16(u0[4], u0[5]); U0.w = pk_bf16(u0[6], u0[7]);
    U1.x = pk_bf16(u1[0], u1[1]); U1.y = pk_bf16(u1[2], u1[3]);
    U1.z = pk_bf16(u1[4], u1[5]); U1.w = pk_bf16(u1[6], u1[7]);
    const short8 B0 = __builtin_bit_cast(short8, U0);   // B[k=j][n=i], lane n=L&15, k=quad*8+q
    const short8 B1 = __builtin_bit_cast(short8, U1);

    // D[m=d][n=i] += A(WhT)[m][k] * B(P^T)[k][n]
    acc00 = __builtin_amdgcn_mfma_f32_16x16x32_bf16(A00, B0, acc00, 0, 0, 0);
    acc01 = __builtin_amdgcn_mfma_f32_16x16x32_bf16(A01, B0, acc01, 0, 0, 0);
    acc10 = __builtin_amdgcn_mfma_f32_16x16x32_bf16(A10, B1, acc10, 0, 0, 0);
    acc11 = __builtin_amdgcn_mfma_f32_16x16x32_bf16(A11, B1, acc11, 0, 0, 0);
  }

  // ---- softmax denominators: lanes {L, L^16, L^32, L^48} share i ----
  l0 += __shfl_xor(l0, 16); l0 += __shfl_xor(l0, 32);
  l1 += __shfl_xor(l1, 16); l1 += __shfl_xor(l1, 32);
  const float inv0 = __builtin_amdgcn_rcpf(l0);
  const float inv1 = __builtin_amdgcn_rcpf(l1);

  // lane holds 16 h-values for row i at f = h*32 + half*16 + quad*4 + r
  float vals[16];
  #pragma unroll
  for (int r = 0; r < 4; ++r) {
    vals[r]      = acc00[r] * inv0;
    vals[4 + r]  = acc01[r] * inv0;
    vals[8 + r]  = acc10[r] * inv1;
    vals[12 + r] = acc11[r] * inv1;
  }

  // ---- LayerNorm partials: reduce over quads then across waves via LDS ----
  float s = 0.f, ss = 0.f;
  #pragma unroll
  for (int k = 0; k < 16; ++k) { s += vals[k]; ss += vals[k] * vals[k]; }
  s += __shfl_xor(s, 16); ss += __shfl_xor(ss, 16);
  s += __shfl_xor(s, 32); ss += __shfl_xor(ss, 32);
  if (quad == 0) { float2 v; v.x = s; v.y = ss; lnS[i * 4 + w] = v; }
  __syncthreads();
  float S = 0.f, SS = 0.f;
  #pragma unroll
  for (int ww = 0; ww < 4; ++ww) { const float2 v = lnS[i * 4 + ww]; S += v.x; SS += v.y; }
  const float mu   = S * (1.0f / 256.0f);
  const float var  = SS * (1.0f / 256.0f) - mu * mu;
  const float rstd = rsqrtf(var + 1e-5f);

  // ---- scale/shift + ELU + store (4 float4 runs per lane) ----
  const int fb[4] = { h0 * 32 + quad * 4, h0 * 32 + 16 + quad * 4,
                      h1 * 32 + quad * 4, h1 * 32 + 16 + quad * 4 };
  #pragma unroll
  for (int g = 0; g < 4; ++g) {
    const float4 gv = *(const float4*)(gam + fb[g]);
    const float4 bv = *(const float4*)(bet + fb[g]);
    float4 o;
    o.x = (vals[g*4+0] - mu) * rstd * gv.x + bv.x;
    o.y = (vals[g*4+1] - mu) * rstd * gv.y + bv.y;
    o.z = (vals[g*4+2] - mu) * rstd * gv.z + bv.z;
    o.w = (vals[g*4+3] - mu) * rstd * gv.w + bv.w;
    o.x = o.x > 0.f ? o.x : exp2f(o.x * L2E) - 1.f;
    o.y = o.y > 0.f ? o.y : exp2f(o.y * L2E) - 1.f;
    o.z = o.z > 0.f ? o.z : exp2f(o.z * L2E) - 1.f;
    o.w = o.w > 0.f ? o.w : exp2f(o.w * L2E) - 1.f;
    *(float4*)(out + (size_t)row * FOUT + fb[g]) = o;
  }
}

extern "C" void kernel_launch(void* const* d_in, const int* in_sizes, int n_in,
                              void* d_out, int out_size, void* d_ws, size_t ws_size,
                              hipStream_t stream) {
  (void)in_sizes; (void)n_in; (void)out_size; (void)ws_size;
  const float* x   = (const float*)d_in[0];
  const int*   adj = (const int*)  d_in[1];
  const int*   ety = (const int*)  d_in[2];
  const float* Wm  = (const float*)d_in[3];
  const float* a1  = (const float*)d_in[4];
  const float* a2  = (const float*)d_in[5];
  const float* emb = (const float*)d_in[6];
  const float* gam = (const float*)d_in[7];
  const float* bet = (const float*)d_in[8];
  float* out = (float*)d_out;

  unsigned short* WhT = (unsigned short*)d_ws;              // 16*8*32*512 bf16 = 4 MB
  float* s1  = (float*)(WhT + (size_t)NB * H * 32 * 512);   // 8192*8 fp32 (pre-scaled)
  float* s2T = s1 + (size_t)NB * NN * H;                    // 16*8*512 fp32 (pre-scaled)

  k_gemm<<<dim3(NB * NN / 16), dim3(256), 0, stream>>>(x, Wm, a1, a2, WhT, s1, s2T);
  k_attn<<<dim3(NB * (NN / 16)), dim3(256), 0, stream>>>(adj, ety, s1, s2T, WhT, emb, gam, bet, out);
}

// Round 3
// 141.453 us; speedup vs baseline: 1.3467x; 1.1904x over previous
//
#include <hip/hip_runtime.h>
#include <hip/hip_bf16.h>
#include <stdint.h>

namespace gat {
constexpr int NB   = 16;
constexpr int NN   = 512;
constexpr int FIN  = 256;
constexpr int FOUT = 256;
constexpr int H    = 8;
constexpr int NE   = 50;
constexpr float L2E  = 1.4426950408889634f;   // log2(e); s1,s2,emb pre-scaled so exp(e)=exp2(e')
constexpr float MASK = -115.41500f;           // -80 * log2e; exp2 -> 2.4e-35 (normal fp32)
}
using namespace gat;

typedef __attribute__((ext_vector_type(8))) short short8;  // 8 bf16 = 4 VGPRs (MFMA A/B frag)
typedef __attribute__((ext_vector_type(4))) float f32x4;   // MFMA C/D frag

__device__ __forceinline__ unsigned pk_bf16(unsigned ulo, unsigned uhi) {
  // inputs are float bits + 0x8000 (round-half-up); take high halves, lo in low
  return __builtin_amdgcn_perm(uhi, ulo, 0x07060302u);
}
__device__ __forceinline__ unsigned pk2f(float a, float b) {
  return pk_bf16(__float_as_uint(a) + 0x8000u, __float_as_uint(b) + 0x8000u);
}

// ---------------- Kernel P: WbT[f][k] = bf16(W[k][f]) (one-time 256x256 transpose) ----------
__global__ __launch_bounds__(256) void k_prep(const float* __restrict__ Wm,
                                              unsigned short* __restrict__ WbT) {
  const int k  = threadIdx.x;
  const int f0 = blockIdx.x * 4;
  #pragma unroll
  for (int r = 0; r < 4; ++r) {
    const unsigned u = __float_as_uint(Wm[k * FOUT + f0 + r]) + 0x8000u;
    WbT[(f0 + r) * FIN + k] = (unsigned short)(u >> 16);
  }
}

// ---------------- Kernel A (MFMA): Wh = x@W -> WhT bf16 [b][h][d][n]; s1; s2T --------------
// 512 blocks x 256. Block: 16 node-rows. Wave w: F-slice [w*64, w*64+64) = heads {2w, 2w+1}.
// A-frag (x rows) from LDS bf16 stage; B-frag (WbT) 16B global loads (L2-resident 128 KB).
__global__ __launch_bounds__(256, 4) void k_gemm(
    const float* __restrict__ x, const unsigned short* __restrict__ WbT,
    const float* __restrict__ a1, const float* __restrict__ a2,
    unsigned short* __restrict__ WhT, float* __restrict__ s1, float* __restrict__ s2T)
{
  __shared__ alignas(16) unsigned short xS[16 * 264];  // row stride 264 -> 2-way conflicts only
  const int t    = threadIdx.x;
  const int row0 = blockIdx.x * 16;

  { // stage 16 rows of x, fp32 -> bf16
    const int r  = t >> 4;
    const int kb = (t & 15) * 16;
    const float4* xg = (const float4*)(x + (size_t)(row0 + r) * FIN + kb);
    const float4 v0 = xg[0], v1 = xg[1], v2 = xg[2], v3 = xg[3];
    uint4 o0, o1;
    o0.x = pk2f(v0.x, v0.y); o0.y = pk2f(v0.z, v0.w);
    o0.z = pk2f(v1.x, v1.y); o0.w = pk2f(v1.z, v1.w);
    o1.x = pk2f(v2.x, v2.y); o1.y = pk2f(v2.z, v2.w);
    o1.z = pk2f(v3.x, v3.y); o1.w = pk2f(v3.z, v3.w);
    *(uint4*)&xS[r * 264 + kb]     = o0;
    *(uint4*)&xS[r * 264 + kb + 8] = o1;
  }
  __syncthreads();

  const int w    = t >> 6;
  const int L    = t & 63;
  const int nn   = L & 15;     // A: node row; B: f col (within tile)
  const int quad = L >> 4;     // k sub-chunk; D: node row group
  const unsigned short* wb = WbT + (size_t)(w * 64 + nn) * FIN + quad * 8;
  const unsigned short* xp = &xS[nn * 264 + quad * 8];

  f32x4 acc0 = {0.f,0.f,0.f,0.f}, acc1 = {0.f,0.f,0.f,0.f};
  f32x4 acc2 = {0.f,0.f,0.f,0.f}, acc3 = {0.f,0.f,0.f,0.f};

  #pragma unroll 2
  for (int kc = 0; kc < 8; ++kc) {
    const int k0 = kc * 32;
    const short8 A  = *(const short8*)(xp + k0);
    const short8 B0 = *(const short8*)(wb + k0);
    const short8 B1 = *(const short8*)(wb + 16 * FIN + k0);
    const short8 B2 = *(const short8*)(wb + 32 * FIN + k0);
    const short8 B3 = *(const short8*)(wb + 48 * FIN + k0);
    acc0 = __builtin_amdgcn_mfma_f32_16x16x32_bf16(A, B0, acc0, 0, 0, 0);
    acc1 = __builtin_amdgcn_mfma_f32_16x16x32_bf16(A, B1, acc1, 0, 0, 0);
    acc2 = __builtin_amdgcn_mfma_f32_16x16x32_bf16(A, B2, acc2, 0, 0, 0);
    acc3 = __builtin_amdgcn_mfma_f32_16x16x32_bf16(A, B3, acc3, 0, 0, 0);
  }

  // D layout: lane holds col f = w*64 + ft*16 + nn, rows (nodes) = quad*4 + r
  const int b     = row0 >> 9;
  const int node0 = (row0 & 511) + quad * 4;
  f32x4 accs[4] = {acc0, acc1, acc2, acc3};

  // WhT bf16: pack 4 consecutive nodes per lane -> 8 B store
  #pragma unroll
  for (int ft = 0; ft < 4; ++ft) {
    const int f = w * 64 + ft * 16 + nn;
    uint2 o;
    o.x = pk2f(accs[ft][0], accs[ft][1]);
    o.y = pk2f(accs[ft][2], accs[ft][3]);
    *(uint2*)(WhT + (size_t)((b * 8 + (f >> 5)) * 32 + (f & 31)) * 512 + node0) = o;
  }

  // s1/s2 (pre-scaled by log2e): head h covers 2 tiles; reduce over 16 lanes (d = tile*16+nn)
  const float a1lo = a1[nn], a1hi = a1[16 + nn];
  const float a2lo = a2[nn], a2hi = a2[16 + nn];
  #pragma unroll
  for (int hh = 0; hh < 2; ++hh) {
    const int h = w * 2 + hh;
    const f32x4 e0 = accs[hh * 2], e1 = accs[hh * 2 + 1];
    float p1[4], p2[4];
    #pragma unroll
    for (int r = 0; r < 4; ++r) {
      p1[r] = e0[r] * a1lo + e1[r] * a1hi;
      p2[r] = e0[r] * a2lo + e1[r] * a2hi;
    }
    #pragma unroll
    for (int r = 0; r < 4; ++r) {
      p1[r] += __shfl_xor(p1[r], 1); p2[r] += __shfl_xor(p2[r], 1);
      p1[r] += __shfl_xor(p1[r], 2); p2[r] += __shfl_xor(p2[r], 2);
      p1[r] += __shfl_xor(p1[r], 4); p2[r] += __shfl_xor(p2[r], 4);
      p1[r] += __shfl_xor(p1[r], 8); p2[r] += __shfl_xor(p2[r], 8);
    }
    if (nn == 0) {
      float4 sv; sv.x = p2[0] * L2E; sv.y = p2[1] * L2E; sv.z = p2[2] * L2E; sv.w = p2[3] * L2E;
      *(float4*)(s2T + (size_t)(b * 8 + h) * 512 + node0) = sv;
      #pragma unroll
      for (int r = 0; r < 4; ++r)
        s1[(size_t)(row0 + quad * 4 + r) * H + h] = p1[r] * L2E;
    }
  }
}

// ---------------- Kernel B: e-phase -> MFMA aggregate -> softmax-norm -> LN -> ELU ----------
// (unchanged from round 2 — passed; counters next round will target it)
__global__ __launch_bounds__(256, 2) void k_attn(
    const int* __restrict__ adj, const int* __restrict__ ety,
    const float* __restrict__ s1, const float* __restrict__ s2T,
    const unsigned short* __restrict__ WhT, const float* __restrict__ emb,
    const float* __restrict__ gam, const float* __restrict__ bet,
    float* __restrict__ out)
{
  __shared__ float2 embS[4 * 64];   // [wave][et] = (emb[et][w], emb[et][w+4]) * L2E
  __shared__ float2 lnS[16 * 4];    // [i][wave] partial (sum, sumsq)

  const int t    = threadIdx.x;
  const int b    = blockIdx.x >> 5;
  const int i0   = (blockIdx.x & 31) * 16;
  const int w    = t >> 6;
  const int L    = t & 63;
  const int i    = L & 15;
  const int quad = L >> 4;
  const int h0   = w, h1 = w + 4;

  { // stage emb (pair-packed per wave's 2 heads, pre-scaled)
    const int wp = t >> 6, e = t & 63;
    if (e < NE) {
      float2 v; v.x = emb[e * H + wp] * L2E; v.y = emb[e * H + wp + 4] * L2E;
      embS[t] = v;
    }
  }

  const int row = b * NN + i0 + i;           // this lane's i-row (global)
  const float si0 = s1[(size_t)row * H + h0];
  const float si1 = s1[(size_t)row * H + h1];
  const int adjBase = row * NN;
  const float* s2h0 = s2T + (size_t)(b * 8 + h0) * 512;
  const float* s2h1 = s2T + (size_t)(b * 8 + h1) * 512;
  const unsigned short* wt00 = WhT + (size_t)((b * 8 + h0) * 32 + i)      * 512; // d = i
  const unsigned short* wt01 = WhT + (size_t)((b * 8 + h0) * 32 + 16 + i) * 512; // d = 16+i
  const unsigned short* wt10 = WhT + (size_t)((b * 8 + h1) * 32 + i)      * 512;
  const unsigned short* wt11 = WhT + (size_t)((b * 8 + h1) * 32 + 16 + i) * 512;

  f32x4 acc00 = {0.f,0.f,0.f,0.f}, acc01 = {0.f,0.f,0.f,0.f};
  f32x4 acc10 = {0.f,0.f,0.f,0.f}, acc11 = {0.f,0.f,0.f,0.f};
  float l0 = 0.f, l1 = 0.f;

  __syncthreads();

  #pragma unroll 2
  for (int kc = 0; kc < 16; ++kc) {
    const int ja = kc * 32 + quad * 8;
    // ---- loads (issued up front so the scheduler can overlap with e-compute/MFMA) ----
    const int4 av0 = *(const int4*)(adj + adjBase + ja);
    const int4 av1 = *(const int4*)(adj + adjBase + ja + 4);
    const int4 ev0 = *(const int4*)(ety + adjBase + ja);
    const int4 ev1 = *(const int4*)(ety + adjBase + ja + 4);
    const float4 sa0 = *(const float4*)(s2h0 + ja);
    const float4 sb0 = *(const float4*)(s2h0 + ja + 4);
    const float4 sa1 = *(const float4*)(s2h1 + ja);
    const float4 sb1 = *(const float4*)(s2h1 + ja + 4);
    const short8 A00 = *(const short8*)(wt00 + ja);
    const short8 A01 = *(const short8*)(wt01 + ja);
    const short8 A10 = *(const short8*)(wt10 + ja);
    const short8 A11 = *(const short8*)(wt11 + ja);

    const int aq[8] = {av0.x, av0.y, av0.z, av0.w, av1.x, av1.y, av1.z, av1.w};
    const int eq[8] = {ev0.x, ev0.y, ev0.z, ev0.w, ev1.x, ev1.y, ev1.z, ev1.w};
    const float s20[8] = {sa0.x, sa0.y, sa0.z, sa0.w, sb0.x, sb0.y, sb0.z, sb0.w};
    const float s21[8] = {sa1.x, sa1.y, sa1.z, sa1.w, sb1.x, sb1.y, sb1.z, sb1.w};

    unsigned u0[8], u1[8];
    #pragma unroll
    for (int q = 0; q < 8; ++q) {
      const float2 em = embS[w * 64 + eq[q]];
      const bool on = (aq[q] != 0);
      float e0 = si0 + s20[q] + em.x;
      float e1 = si1 + s21[q] + em.y;
      e0 = fmaxf(e0, 0.2f * e0);              // leaky (scale-commutes with L2E)
      e1 = fmaxf(e1, 0.2f * e1);
      e0 = on ? e0 : MASK;
      e1 = on ? e1 : MASK;
      const float p0 = exp2f(e0);             // v_exp_f32
      const float p1 = exp2f(e1);
      l0 += p0; l1 += p1;
      u0[q] = __float_as_uint(p0) + 0x8000u;  // round-half-up bf16 prep
      u1[q] = __float_as_uint(p1) + 0x8000u;
    }
    uint4 U0, U1;
    U0.x = pk_bf16(u0[0], u0[1]); U0.y = pk_bf16(u0[2], u0[3]);
    U0.z = pk_bf16(u0[4], u0[5]); U0.w = pk_bf16(u0[6], u0[7]);
    U1.x = pk_bf16(u1[0], u1[1]); U1.y = pk_bf16(u1[2], u1[3]);
    U1.z = pk_bf16(u1[4], u1[5]); U1.w = pk_bf16(u1[6], u1[7]);
    const short8 B0 = __builtin_bit_cast(short8, U0);   // B[k=j][n=i], lane n=L&15, k=quad*8+q
    const short8 B1 = __builtin_bit_cast(short8, U1);

    // D[m=d][n=i] += A(WhT)[m][k] * B(P^T)[k][n]
    acc00 = __builtin_amdgcn_mfma_f32_16x16x32_bf16(A00, B0, acc00, 0, 0, 0);
    acc01 = __builtin_amdgcn_mfma_f32_16x16x32_bf16(A01, B0, acc01, 0, 0, 0);
    acc10 = __builtin_amdgcn_mfma_f32_16x16x32_bf16(A10, B1, acc10, 0, 0, 0);
    acc11 = __builtin_amdgcn_mfma_f32_16x16x32_bf16(A11, B1, acc11, 0, 0, 0);
  }

  // ---- softmax denominators: lanes {L, L^16, L^32, L^48} share i ----
  l0 += __shfl_xor(l0, 16); l0 += __shfl_xor(l0, 32);
  l1 += __shfl_xor(l1, 16); l1 += __shfl_xor(l1, 32);
  const float inv0 = __builtin_amdgcn_rcpf(l0);
  const float inv1 = __builtin_amdgcn_rcpf(l1);

  // lane holds 16 h-values for row i at f = h*32 + half*16 + quad*4 + r
  float vals[16];
  #pragma unroll
  for (int r = 0; r < 4; ++r) {
    vals[r]      = acc00[r] * inv0;
    vals[4 + r]  = acc01[r] * inv0;
    vals[8 + r]  = acc10[r] * inv1;
    vals[12 + r] = acc11[r] * inv1;
  }

  // ---- LayerNorm partials: reduce over quads then across waves via LDS ----
  float s = 0.f, ss = 0.f;
  #pragma unroll
  for (int k = 0; k < 16; ++k) { s += vals[k]; ss += vals[k] * vals[k]; }
  s += __shfl_xor(s, 16); ss += __shfl_xor(ss, 16);
  s += __shfl_xor(s, 32); ss += __shfl_xor(ss, 32);
  if (quad == 0) { float2 v; v.x = s; v.y = ss; lnS[i * 4 + w] = v; }
  __syncthreads();
  float S = 0.f, SS = 0.f;
  #pragma unroll
  for (int ww = 0; ww < 4; ++ww) { const float2 v = lnS[i * 4 + ww]; S += v.x; SS += v.y; }
  const float mu   = S * (1.0f / 256.0f);
  const float var  = SS * (1.0f / 256.0f) - mu * mu;
  const float rstd = rsqrtf(var + 1e-5f);

  // ---- scale/shift + ELU + store (4 float4 runs per lane) ----
  const int fb[4] = { h0 * 32 + quad * 4, h0 * 32 + 16 + quad * 4,
                      h1 * 32 + quad * 4, h1 * 32 + 16 + quad * 4 };
  #pragma unroll
  for (int g = 0; g < 4; ++g) {
    const float4 gv = *(const float4*)(gam + fb[g]);
    const float4 bv = *(const float4*)(bet + fb[g]);
    float4 o;
    o.x = (vals[g*4+0] - mu) * rstd * gv.x + bv.x;
    o.y = (vals[g*4+1] - mu) * rstd * gv.y + bv.y;
    o.z = (vals[g*4+2] - mu) * rstd * gv.z + bv.z;
    o.w = (vals[g*4+3] - mu) * rstd * gv.w + bv.w;
    o.x = o.x > 0.f ? o.x : exp2f(o.x * L2E) - 1.f;
    o.y = o.y > 0.f ? o.y : exp2f(o.y * L2E) - 1.f;
    o.z = o.z > 0.f ? o.z : exp2f(o.z * L2E) - 1.f;
    o.w = o.w > 0.f ? o.w : exp2f(o.w * L2E) - 1.f;
    *(float4*)(out + (size_t)row * FOUT + fb[g]) = o;
  }
}

extern "C" void kernel_launch(void* const* d_in, const int* in_sizes, int n_in,
                              void* d_out, int out_size, void* d_ws, size_t ws_size,
                              hipStream_t stream) {
  (void)in_sizes; (void)n_in; (void)out_size; (void)ws_size;
  const float* x   = (const float*)d_in[0];
  const int*   adj = (const int*)  d_in[1];
  const int*   ety = (const int*)  d_in[2];
  const float* Wm  = (const float*)d_in[3];
  const float* a1  = (const float*)d_in[4];
  const float* a2  = (const float*)d_in[5];
  const float* emb = (const float*)d_in[6];
  const float* gam = (const float*)d_in[7];
  const float* bet = (const float*)d_in[8];
  float* out = (float*)d_out;

  unsigned short* WhT = (unsigned short*)d_ws;              // 16*8*32*512 bf16 = 4 MB
  unsigned short* WbT = WhT + (size_t)NB * H * 32 * 512;    // 256*256 bf16 = 128 KB
  float* s1  = (float*)(WbT + (size_t)FOUT * FIN);          // 8192*8 fp32 (pre-scaled)
  float* s2T = s1 + (size_t)NB * NN * H;                    // 16*8*512 fp32 (pre-scaled)

  k_prep<<<dim3(64),  dim3(256), 0, stream>>>(Wm, WbT);
  k_gemm<<<dim3(NB * NN / 16), dim3(256), 0, stream>>>(x, WbT, a1, a2, WhT, s1, s2T);
  k_attn<<<dim3(NB * (NN / 16)), dim3(256), 0, stream>>>(adj, ety, s1, s2T, WhT, emb, gam, bet, out);
}

// Round 4
// 139.394 us; speedup vs baseline: 1.3666x; 1.0148x over previous
//
#include <hip/hip_runtime.h>
#include <hip/hip_bf16.h>
#include <stdint.h>

namespace gat {
constexpr int NB   = 16;
constexpr int NN   = 512;
constexpr int FIN  = 256;
constexpr int FOUT = 256;
constexpr int H    = 8;
constexpr int NE   = 50;
constexpr float L2E  = 1.4426950408889634f;   // log2(e); s1,s2,emb pre-scaled so exp(e)=exp2(e')
constexpr float MASK = -115.41500f;           // -80 * log2e; exp2 -> 2.4e-35 (normal fp32)
}
using namespace gat;

typedef __attribute__((ext_vector_type(8))) short short8;  // 8 bf16 = 4 VGPRs (MFMA A/B frag)
typedef __attribute__((ext_vector_type(4))) float f32x4;   // MFMA C/D frag

__device__ __forceinline__ unsigned pk_bf16(unsigned ulo, unsigned uhi) {
  return __builtin_amdgcn_perm(uhi, ulo, 0x07060302u);
}
__device__ __forceinline__ unsigned pk2f(float a, float b) {
  return pk_bf16(__float_as_uint(a) + 0x8000u, __float_as_uint(b) + 0x8000u);
}

// ---------------- Kernel P: WbT[f][k] = bf16(W[k][f]) ----------------
// Coalesced row read; scattered 2B stores are fire-and-forget (L2 write-combines).
__global__ __launch_bounds__(256) void k_prep(const float* __restrict__ Wm,
                                              unsigned short* __restrict__ WbT) {
  const int k = blockIdx.x;
  const int f = threadIdx.x;
  const unsigned u = __float_as_uint(Wm[k * FOUT + f]) + 0x8000u;
  WbT[f * FIN + k] = (unsigned short)(u >> 16);
}

// ---------------- Kernel A (MFMA, K-split): Wh = x@W -> WhT bf16; s1; s2T --------------
// 512 blocks x 512 thr (8 waves). Wave (w = W&3: 64-f slice, kh = W>>2: K-half).
// Partials combined via LDS; epilogue on kh==0 waves.
__global__ __launch_bounds__(512, 4) void k_gemm(
    const float* __restrict__ x, const unsigned short* __restrict__ WbT,
    const float* __restrict__ a1, const float* __restrict__ a2,
    unsigned short* __restrict__ WhT, float* __restrict__ s1, float* __restrict__ s2T)
{
  __shared__ alignas(16) unsigned short xS[16 * 264];  // row stride 264 -> 2-way only
  __shared__ float redG[256 * 18];                     // stride 18 -> 2-way only
  const int t    = threadIdx.x;
  const int row0 = blockIdx.x * 16;

  { // stage 16 rows of x, fp32 -> bf16 (512 threads, 8 k's each)
    const int r  = t >> 5;
    const int kb = (t & 31) * 8;
    const float4* xg = (const float4*)(x + (size_t)(row0 + r) * FIN + kb);
    const float4 v0 = xg[0], v1 = xg[1];
    uint4 o;
    o.x = pk2f(v0.x, v0.y); o.y = pk2f(v0.z, v0.w);
    o.z = pk2f(v1.x, v1.y); o.w = pk2f(v1.z, v1.w);
    *(uint4*)&xS[r * 264 + kb] = o;
  }
  __syncthreads();

  const int W    = t >> 6;
  const int w    = W & 3;      // f-slice
  const int kh   = W >> 2;     // K-half
  const int L    = t & 63;
  const int nn   = L & 15;     // A: node row; B: f col (within tile)
  const int quad = L >> 4;     // k sub-chunk; D: node row group
  const unsigned short* wb = WbT + (size_t)(w * 64 + nn) * FIN + kh * 128 + quad * 8;
  const unsigned short* xp = &xS[nn * 264 + kh * 128 + quad * 8];

  f32x4 acc0 = {0.f,0.f,0.f,0.f}, acc1 = {0.f,0.f,0.f,0.f};
  f32x4 acc2 = {0.f,0.f,0.f,0.f}, acc3 = {0.f,0.f,0.f,0.f};

  #pragma unroll
  for (int kc = 0; kc < 4; ++kc) {
    const int k0 = kc * 32;
    const short8 A  = *(const short8*)(xp + k0);
    const short8 B0 = *(const short8*)(wb + k0);
    const short8 B1 = *(const short8*)(wb + 16 * FIN + k0);
    const short8 B2 = *(const short8*)(wb + 32 * FIN + k0);
    const short8 B3 = *(const short8*)(wb + 48 * FIN + k0);
    acc0 = __builtin_amdgcn_mfma_f32_16x16x32_bf16(A, B0, acc0, 0, 0, 0);
    acc1 = __builtin_amdgcn_mfma_f32_16x16x32_bf16(A, B1, acc1, 0, 0, 0);
    acc2 = __builtin_amdgcn_mfma_f32_16x16x32_bf16(A, B2, acc2, 0, 0, 0);
    acc3 = __builtin_amdgcn_mfma_f32_16x16x32_bf16(A, B3, acc3, 0, 0, 0);
  }

  const int tt = (w << 6) | L;
  if (kh == 1) {
    float* rp = redG + tt * 18;
    #pragma unroll
    for (int r = 0; r < 4; ++r) {
      ((float2*)rp)[r]     = {acc0[r * 2 & 3], 0.f}; // placeholder avoided below
    }
    // explicit stores (compiler folds): 16 floats
    rp[0]=acc0[0]; rp[1]=acc0[1]; rp[2]=acc0[2]; rp[3]=acc0[3];
    rp[4]=acc1[0]; rp[5]=acc1[1]; rp[6]=acc1[2]; rp[7]=acc1[3];
    rp[8]=acc2[0]; rp[9]=acc2[1]; rp[10]=acc2[2]; rp[11]=acc2[3];
    rp[12]=acc3[0]; rp[13]=acc3[1]; rp[14]=acc3[2]; rp[15]=acc3[3];
  }
  __syncthreads();
  if (kh == 1) return;

  {
    const float* rp = redG + tt * 18;
    acc0[0]+=rp[0]; acc0[1]+=rp[1]; acc0[2]+=rp[2]; acc0[3]+=rp[3];
    acc1[0]+=rp[4]; acc1[1]+=rp[5]; acc1[2]+=rp[6]; acc1[3]+=rp[7];
    acc2[0]+=rp[8]; acc2[1]+=rp[9]; acc2[2]+=rp[10]; acc2[3]+=rp[11];
    acc3[0]+=rp[12]; acc3[1]+=rp[13]; acc3[2]+=rp[14]; acc3[3]+=rp[15];
  }

  // D layout: lane holds col f = w*64 + ft*16 + nn, rows (nodes) = quad*4 + r
  const int b     = row0 >> 9;
  const int node0 = (row0 & 511) + quad * 4;
  f32x4 accs[4] = {acc0, acc1, acc2, acc3};

  #pragma unroll
  for (int ft = 0; ft < 4; ++ft) {
    const int f = w * 64 + ft * 16 + nn;
    uint2 o;
    o.x = pk2f(accs[ft][0], accs[ft][1]);
    o.y = pk2f(accs[ft][2], accs[ft][3]);
    *(uint2*)(WhT + (size_t)((b * 8 + (f >> 5)) * 32 + (f & 31)) * 512 + node0) = o;
  }

  const float a1lo = a1[nn], a1hi = a1[16 + nn];
  const float a2lo = a2[nn], a2hi = a2[16 + nn];
  #pragma unroll
  for (int hh = 0; hh < 2; ++hh) {
    const int h = w * 2 + hh;
    const f32x4 e0 = accs[hh * 2], e1 = accs[hh * 2 + 1];
    float p1[4], p2[4];
    #pragma unroll
    for (int r = 0; r < 4; ++r) {
      p1[r] = e0[r] * a1lo + e1[r] * a1hi;
      p2[r] = e0[r] * a2lo + e1[r] * a2hi;
    }
    #pragma unroll
    for (int r = 0; r < 4; ++r) {
      p1[r] += __shfl_xor(p1[r], 1); p2[r] += __shfl_xor(p2[r], 1);
      p1[r] += __shfl_xor(p1[r], 2); p2[r] += __shfl_xor(p2[r], 2);
      p1[r] += __shfl_xor(p1[r], 4); p2[r] += __shfl_xor(p2[r], 4);
      p1[r] += __shfl_xor(p1[r], 8); p2[r] += __shfl_xor(p2[r], 8);
    }
    if (nn == 0) {
      float4 sv; sv.x = p2[0] * L2E; sv.y = p2[1] * L2E; sv.z = p2[2] * L2E; sv.w = p2[3] * L2E;
      *(float4*)(s2T + (size_t)(b * 8 + h) * 512 + node0) = sv;
      #pragma unroll
      for (int r = 0; r < 4; ++r)
        s1[(size_t)(row0 + quad * 4 + r) * H + h] = p1[r] * L2E;
    }
  }
}

// ---------------- Kernel B (j-split): e-phase -> MFMA aggregate -> softmax -> LN -> ELU ----
// 512 blocks x 512 thr (8 waves). Wave (w = W&3: heads {w, w+4}, jh = W>>2: j-half of 256).
// Partial (acc, l) combined across halves via LDS; epilogue on jh==0 waves.
__global__ __launch_bounds__(512, 4) void k_attn(
    const int* __restrict__ adj, const int* __restrict__ ety,
    const float* __restrict__ s1, const float* __restrict__ s2T,
    const unsigned short* __restrict__ WhT, const float* __restrict__ emb,
    const float* __restrict__ gam, const float* __restrict__ bet,
    float* __restrict__ out)
{
  __shared__ float2 embS[4 * 64];   // [w][et] = (emb[et][w], emb[et][w+4]) * L2E
  __shared__ float2 lnS[16 * 4];    // [i][w] partial (sum, sumsq)
  __shared__ float  redS[256 * 18]; // [tt][18]: 16 accs + l0 + l1; stride 18 -> 2-way only

  const int t    = threadIdx.x;
  const int b    = blockIdx.x >> 5;
  const int i0   = (blockIdx.x & 31) * 16;
  const int W    = t >> 6;
  const int w    = W & 3;
  const int jh   = W >> 2;
  const int L    = t & 63;
  const int i    = L & 15;
  const int quad = L >> 4;
  const int h0   = w, h1 = w + 4;

  if (t < 256) { // stage emb (pair-packed per head-pair, pre-scaled)
    const int wp = t >> 6, e = t & 63;
    if (e < NE) {
      float2 v; v.x = emb[e * H + wp] * L2E; v.y = emb[e * H + wp + 4] * L2E;
      embS[t] = v;
    }
  }

  const int row = b * NN + i0 + i;
  const float si0 = s1[(size_t)row * H + h0];
  const float si1 = s1[(size_t)row * H + h1];
  const int adjBase = row * NN;
  const int jbase   = jh * 256;
  const float* s2h0 = s2T + (size_t)(b * 8 + h0) * 512;
  const float* s2h1 = s2T + (size_t)(b * 8 + h1) * 512;
  const unsigned short* wt00 = WhT + (size_t)((b * 8 + h0) * 32 + i)      * 512;
  const unsigned short* wt01 = WhT + (size_t)((b * 8 + h0) * 32 + 16 + i) * 512;
  const unsigned short* wt10 = WhT + (size_t)((b * 8 + h1) * 32 + i)      * 512;
  const unsigned short* wt11 = WhT + (size_t)((b * 8 + h1) * 32 + 16 + i) * 512;

  f32x4 acc00 = {0.f,0.f,0.f,0.f}, acc01 = {0.f,0.f,0.f,0.f};
  f32x4 acc10 = {0.f,0.f,0.f,0.f}, acc11 = {0.f,0.f,0.f,0.f};
  float l0 = 0.f, l1 = 0.f;

  __syncthreads();

  #pragma unroll 2
  for (int kc = 0; kc < 8; ++kc) {
    const int ja = jbase + kc * 32 + quad * 8;
    const int4 av0 = *(const int4*)(adj + adjBase + ja);
    const int4 av1 = *(const int4*)(adj + adjBase + ja + 4);
    const int4 ev0 = *(const int4*)(ety + adjBase + ja);
    const int4 ev1 = *(const int4*)(ety + adjBase + ja + 4);
    const float4 sa0 = *(const float4*)(s2h0 + ja);
    const float4 sb0 = *(const float4*)(s2h0 + ja + 4);
    const float4 sa1 = *(const float4*)(s2h1 + ja);
    const float4 sb1 = *(const float4*)(s2h1 + ja + 4);
    const short8 A00 = *(const short8*)(wt00 + ja);
    const short8 A01 = *(const short8*)(wt01 + ja);
    const short8 A10 = *(const short8*)(wt10 + ja);
    const short8 A11 = *(const short8*)(wt11 + ja);

    const int aq[8] = {av0.x, av0.y, av0.z, av0.w, av1.x, av1.y, av1.z, av1.w};
    const int eq[8] = {ev0.x, ev0.y, ev0.z, ev0.w, ev1.x, ev1.y, ev1.z, ev1.w};
    const float s20[8] = {sa0.x, sa0.y, sa0.z, sa0.w, sb0.x, sb0.y, sb0.z, sb0.w};
    const float s21[8] = {sa1.x, sa1.y, sa1.z, sa1.w, sb1.x, sb1.y, sb1.z, sb1.w};

    unsigned u0[8], u1[8];
    #pragma unroll
    for (int q = 0; q < 8; ++q) {
      const float2 em = embS[w * 64 + eq[q]];
      const bool on = (aq[q] != 0);
      float e0 = si0 + s20[q] + em.x;
      float e1 = si1 + s21[q] + em.y;
      e0 = fmaxf(e0, 0.2f * e0);
      e1 = fmaxf(e1, 0.2f * e1);
      e0 = on ? e0 : MASK;
      e1 = on ? e1 : MASK;
      const float p0 = exp2f(e0);
      const float p1 = exp2f(e1);
      l0 += p0; l1 += p1;
      u0[q] = __float_as_uint(p0) + 0x8000u;
      u1[q] = __float_as_uint(p1) + 0x8000u;
    }
    uint4 U0, U1;
    U0.x = pk_bf16(u0[0], u0[1]); U0.y = pk_bf16(u0[2], u0[3]);
    U0.z = pk_bf16(u0[4], u0[5]); U0.w = pk_bf16(u0[6], u0[7]);
    U1.x = pk_bf16(u1[0], u1[1]); U1.y = pk_bf16(u1[2], u1[3]);
    U1.z = pk_bf16(u1[4], u1[5]); U1.w = pk_bf16(u1[6], u1[7]);
    const short8 B0 = __builtin_bit_cast(short8, U0);
    const short8 B1 = __builtin_bit_cast(short8, U1);

    acc00 = __builtin_amdgcn_mfma_f32_16x16x32_bf16(A00, B0, acc00, 0, 0, 0);
    acc01 = __builtin_amdgcn_mfma_f32_16x16x32_bf16(A01, B0, acc01, 0, 0, 0);
    acc10 = __builtin_amdgcn_mfma_f32_16x16x32_bf16(A10, B1, acc10, 0, 0, 0);
    acc11 = __builtin_amdgcn_mfma_f32_16x16x32_bf16(A11, B1, acc11, 0, 0, 0);
  }

  // intra-wave l reduction: lanes {L, L^16, L^32, L^48} share i
  l0 += __shfl_xor(l0, 16); l0 += __shfl_xor(l0, 32);
  l1 += __shfl_xor(l1, 16); l1 += __shfl_xor(l1, 32);

  // ---- cross-half combine via LDS ----
  const int tt = (w << 6) | L;
  if (jh == 1) {
    float* rp = redS + tt * 18;
    rp[0]=acc00[0]; rp[1]=acc00[1]; rp[2]=acc00[2]; rp[3]=acc00[3];
    rp[4]=acc01[0]; rp[5]=acc01[1]; rp[6]=acc01[2]; rp[7]=acc01[3];
    rp[8]=acc10[0]; rp[9]=acc10[1]; rp[10]=acc10[2]; rp[11]=acc10[3];
    rp[12]=acc11[0]; rp[13]=acc11[1]; rp[14]=acc11[2]; rp[15]=acc11[3];
    rp[16]=l0; rp[17]=l1;
  }
  __syncthreads();

  float vals[16]; float mu, rstd;
  if (jh == 0) {
    const float* rp = redS + tt * 18;
    acc00[0]+=rp[0]; acc00[1]+=rp[1]; acc00[2]+=rp[2]; acc00[3]+=rp[3];
    acc01[0]+=rp[4]; acc01[1]+=rp[5]; acc01[2]+=rp[6]; acc01[3]+=rp[7];
    acc10[0]+=rp[8]; acc10[1]+=rp[9]; acc10[2]+=rp[10]; acc10[3]+=rp[11];
    acc11[0]+=rp[12]; acc11[1]+=rp[13]; acc11[2]+=rp[14]; acc11[3]+=rp[15];
    l0 += rp[16]; l1 += rp[17];
    const float inv0 = __builtin_amdgcn_rcpf(l0);
    const float inv1 = __builtin_amdgcn_rcpf(l1);
    #pragma unroll
    for (int r = 0; r < 4; ++r) {
      vals[r]      = acc00[r] * inv0;
      vals[4 + r]  = acc01[r] * inv0;
      vals[8 + r]  = acc10[r] * inv1;
      vals[12 + r] = acc11[r] * inv1;
    }
    float s = 0.f, ss = 0.f;
    #pragma unroll
    for (int k = 0; k < 16; ++k) { s += vals[k]; ss += vals[k] * vals[k]; }
    s += __shfl_xor(s, 16); ss += __shfl_xor(ss, 16);
    s += __shfl_xor(s, 32); ss += __shfl_xor(ss, 32);
    if (quad == 0) { float2 v; v.x = s; v.y = ss; lnS[i * 4 + w] = v; }
  }
  __syncthreads();
  if (jh == 1) return;

  {
    float S = 0.f, SS = 0.f;
    #pragma unroll
    for (int ww = 0; ww < 4; ++ww) { const float2 v = lnS[i * 4 + ww]; S += v.x; SS += v.y; }
    mu = S * (1.0f / 256.0f);
    const float var = SS * (1.0f / 256.0f) - mu * mu;
    rstd = rsqrtf(var + 1e-5f);
  }

  const int fb[4] = { h0 * 32 + quad * 4, h0 * 32 + 16 + quad * 4,
                      h1 * 32 + quad * 4, h1 * 32 + 16 + quad * 4 };
  #pragma unroll
  for (int g = 0; g < 4; ++g) {
    const float4 gv = *(const float4*)(gam + fb[g]);
    const float4 bv = *(const float4*)(bet + fb[g]);
    float4 o;
    o.x = (vals[g*4+0] - mu) * rstd * gv.x + bv.x;
    o.y = (vals[g*4+1] - mu) * rstd * gv.y + bv.y;
    o.z = (vals[g*4+2] - mu) * rstd * gv.z + bv.z;
    o.w = (vals[g*4+3] - mu) * rstd * gv.w + bv.w;
    o.x = o.x > 0.f ? o.x : exp2f(o.x * L2E) - 1.f;
    o.y = o.y > 0.f ? o.y : exp2f(o.y * L2E) - 1.f;
    o.z = o.z > 0.f ? o.z : exp2f(o.z * L2E) - 1.f;
    o.w = o.w > 0.f ? o.w : exp2f(o.w * L2E) - 1.f;
    *(float4*)(out + (size_t)row * FOUT + fb[g]) = o;
  }
}

extern "C" void kernel_launch(void* const* d_in, const int* in_sizes, int n_in,
                              void* d_out, int out_size, void* d_ws, size_t ws_size,
                              hipStream_t stream) {
  (void)in_sizes; (void)n_in; (void)out_size; (void)ws_size;
  const float* x   = (const float*)d_in[0];
  const int*   adj = (const int*)  d_in[1];
  const int*   ety = (const int*)  d_in[2];
  const float* Wm  = (const float*)d_in[3];
  const float* a1  = (const float*)d_in[4];
  const float* a2  = (const float*)d_in[5];
  const float* emb = (const float*)d_in[6];
  const float* gam = (const float*)d_in[7];
  const float* bet = (const float*)d_in[8];
  float* out = (float*)d_out;

  unsigned short* WhT = (unsigned short*)d_ws;              // 16*8*32*512 bf16 = 4 MB
  unsigned short* WbT = WhT + (size_t)NB * H * 32 * 512;    // 256*256 bf16 = 128 KB
  float* s1  = (float*)(WbT + (size_t)FOUT * FIN);          // 8192*8 fp32 (pre-scaled)
  float* s2T = s1 + (size_t)NB * NN * H;                    // 16*8*512 fp32 (pre-scaled)

  k_prep<<<dim3(FIN),  dim3(256), 0, stream>>>(Wm, WbT);
  k_gemm<<<dim3(NB * NN / 16), dim3(512), 0, stream>>>(x, WbT, a1, a2, WhT, s1, s2T);
  k_attn<<<dim3(NB * (NN / 16)), dim3(512), 0, stream>>>(adj, ety, s1, s2T, WhT, emb, gam, bet, out);
}

// Round 5
// 138.579 us; speedup vs baseline: 1.3746x; 1.0059x over previous
//
#include <hip/hip_runtime.h>
#include <hip/hip_bf16.h>
#include <stdint.h>

namespace gat {
constexpr int NB   = 16;
constexpr int NN   = 512;
constexpr int FIN  = 256;
constexpr int FOUT = 256;
constexpr int H    = 8;
constexpr int NE   = 50;
constexpr float L2E  = 1.4426950408889634f;   // log2(e); s1,s2,emb pre-scaled so exp(e)=exp2(e')
constexpr float MASK = -115.41500f;           // -80 * log2e; exp2 -> 2.4e-35 (normal fp32)
}
using namespace gat;

typedef __attribute__((ext_vector_type(8))) short short8;  // 8 bf16 = 4 VGPRs (MFMA A/B frag)
typedef __attribute__((ext_vector_type(4))) float f32x4;   // MFMA C/D frag

__device__ __forceinline__ unsigned pk_bf16(unsigned ulo, unsigned uhi) {
  return __builtin_amdgcn_perm(uhi, ulo, 0x07060302u);
}
__device__ __forceinline__ unsigned pk2f(float a, float b) {
  return pk_bf16(__float_as_uint(a) + 0x8000u, __float_as_uint(b) + 0x8000u);
}

// ---------------- Kernel P: WbT[f][k] = bf16(W[k][f]) ----------------
__global__ __launch_bounds__(256) void k_prep(const float* __restrict__ Wm,
                                              unsigned short* __restrict__ WbT) {
  const int k = blockIdx.x;
  const int f = threadIdx.x;
  const unsigned u = __float_as_uint(Wm[k * FOUT + f]) + 0x8000u;
  WbT[f * FIN + k] = (unsigned short)(u >> 16);
}

// ---------------- Kernel C: codes = adj<<6 | ety (1 byte per edge) ----------------
// Pure streaming: 33.5 MB read, 4.2 MB write. Shrinks k_attn's latency-critical
// per-iteration HBM stream by 8x and lets it be fully register-prefetched.
__global__ __launch_bounds__(256) void k_pack(const int* __restrict__ adj,
                                              const int* __restrict__ ety,
                                              unsigned* __restrict__ codes) {
  const size_t base = ((size_t)blockIdx.x * 256 + threadIdx.x) * 16;
  const int4* ap = (const int4*)(adj + base);
  const int4* ep = (const int4*)(ety + base);
  unsigned o[4];
  #pragma unroll
  for (int g = 0; g < 4; ++g) {
    const int4 a = ap[g];
    const int4 e = ep[g];
    o[g] = (unsigned)(e.x | (a.x << 6))
         | ((unsigned)(e.y | (a.y << 6)) << 8)
         | ((unsigned)(e.z | (a.z << 6)) << 16)
         | ((unsigned)(e.w | (a.w << 6)) << 24);
  }
  uint4 v; v.x = o[0]; v.y = o[1]; v.z = o[2]; v.w = o[3];
  *(uint4*)(codes + base / 4) = v;
}

// ---------------- Kernel A (MFMA, K-split): Wh = x@W -> WhT bf16; s1; s2T --------------
__global__ __launch_bounds__(512, 4) void k_gemm(
    const float* __restrict__ x, const unsigned short* __restrict__ WbT,
    const float* __restrict__ a1, const float* __restrict__ a2,
    unsigned short* __restrict__ WhT, float* __restrict__ s1, float* __restrict__ s2T)
{
  __shared__ alignas(16) unsigned short xS[16 * 264];  // row stride 264 -> 2-way only
  __shared__ float redG[256 * 18];                     // stride 18 -> 2-way only
  const int t    = threadIdx.x;
  const int row0 = blockIdx.x * 16;

  { // stage 16 rows of x, fp32 -> bf16 (512 threads, 8 k's each)
    const int r  = t >> 5;
    const int kb = (t & 31) * 8;
    const float4* xg = (const float4*)(x + (size_t)(row0 + r) * FIN + kb);
    const float4 v0 = xg[0], v1 = xg[1];
    uint4 o;
    o.x = pk2f(v0.x, v0.y); o.y = pk2f(v0.z, v0.w);
    o.z = pk2f(v1.x, v1.y); o.w = pk2f(v1.z, v1.w);
    *(uint4*)&xS[r * 264 + kb] = o;
  }
  __syncthreads();

  const int W    = t >> 6;
  const int w    = W & 3;      // f-slice
  const int kh   = W >> 2;     // K-half
  const int L    = t & 63;
  const int nn   = L & 15;
  const int quad = L >> 4;
  const unsigned short* wb = WbT + (size_t)(w * 64 + nn) * FIN + kh * 128 + quad * 8;
  const unsigned short* xp = &xS[nn * 264 + kh * 128 + quad * 8];

  f32x4 acc0 = {0.f,0.f,0.f,0.f}, acc1 = {0.f,0.f,0.f,0.f};
  f32x4 acc2 = {0.f,0.f,0.f,0.f}, acc3 = {0.f,0.f,0.f,0.f};

  #pragma unroll
  for (int kc = 0; kc < 4; ++kc) {
    const int k0 = kc * 32;
    const short8 A  = *(const short8*)(xp + k0);
    const short8 B0 = *(const short8*)(wb + k0);
    const short8 B1 = *(const short8*)(wb + 16 * FIN + k0);
    const short8 B2 = *(const short8*)(wb + 32 * FIN + k0);
    const short8 B3 = *(const short8*)(wb + 48 * FIN + k0);
    acc0 = __builtin_amdgcn_mfma_f32_16x16x32_bf16(A, B0, acc0, 0, 0, 0);
    acc1 = __builtin_amdgcn_mfma_f32_16x16x32_bf16(A, B1, acc1, 0, 0, 0);
    acc2 = __builtin_amdgcn_mfma_f32_16x16x32_bf16(A, B2, acc2, 0, 0, 0);
    acc3 = __builtin_amdgcn_mfma_f32_16x16x32_bf16(A, B3, acc3, 0, 0, 0);
  }

  const int tt = (w << 6) | L;
  if (kh == 1) {
    float* rp = redG + tt * 18;
    rp[0]=acc0[0]; rp[1]=acc0[1]; rp[2]=acc0[2]; rp[3]=acc0[3];
    rp[4]=acc1[0]; rp[5]=acc1[1]; rp[6]=acc1[2]; rp[7]=acc1[3];
    rp[8]=acc2[0]; rp[9]=acc2[1]; rp[10]=acc2[2]; rp[11]=acc2[3];
    rp[12]=acc3[0]; rp[13]=acc3[1]; rp[14]=acc3[2]; rp[15]=acc3[3];
  }
  __syncthreads();
  if (kh == 1) return;

  {
    const float* rp = redG + tt * 18;
    acc0[0]+=rp[0]; acc0[1]+=rp[1]; acc0[2]+=rp[2]; acc0[3]+=rp[3];
    acc1[0]+=rp[4]; acc1[1]+=rp[5]; acc1[2]+=rp[6]; acc1[3]+=rp[7];
    acc2[0]+=rp[8]; acc2[1]+=rp[9]; acc2[2]+=rp[10]; acc2[3]+=rp[11];
    acc3[0]+=rp[12]; acc3[1]+=rp[13]; acc3[2]+=rp[14]; acc3[3]+=rp[15];
  }

  const int b     = row0 >> 9;
  const int node0 = (row0 & 511) + quad * 4;
  f32x4 accs[4] = {acc0, acc1, acc2, acc3};

  #pragma unroll
  for (int ft = 0; ft < 4; ++ft) {
    const int f = w * 64 + ft * 16 + nn;
    uint2 o;
    o.x = pk2f(accs[ft][0], accs[ft][1]);
    o.y = pk2f(accs[ft][2], accs[ft][3]);
    *(uint2*)(WhT + (size_t)((b * 8 + (f >> 5)) * 32 + (f & 31)) * 512 + node0) = o;
  }

  const float a1lo = a1[nn], a1hi = a1[16 + nn];
  const float a2lo = a2[nn], a2hi = a2[16 + nn];
  #pragma unroll
  for (int hh = 0; hh < 2; ++hh) {
    const int h = w * 2 + hh;
    const f32x4 e0 = accs[hh * 2], e1 = accs[hh * 2 + 1];
    float p1[4], p2[4];
    #pragma unroll
    for (int r = 0; r < 4; ++r) {
      p1[r] = e0[r] * a1lo + e1[r] * a1hi;
      p2[r] = e0[r] * a2lo + e1[r] * a2hi;
    }
    #pragma unroll
    for (int r = 0; r < 4; ++r) {
      p1[r] += __shfl_xor(p1[r], 1); p2[r] += __shfl_xor(p2[r], 1);
      p1[r] += __shfl_xor(p1[r], 2); p2[r] += __shfl_xor(p2[r], 2);
      p1[r] += __shfl_xor(p1[r], 4); p2[r] += __shfl_xor(p2[r], 4);
      p1[r] += __shfl_xor(p1[r], 8); p2[r] += __shfl_xor(p2[r], 8);
    }
    if (nn == 0) {
      float4 sv; sv.x = p2[0] * L2E; sv.y = p2[1] * L2E; sv.z = p2[2] * L2E; sv.w = p2[3] * L2E;
      *(float4*)(s2T + (size_t)(b * 8 + h) * 512 + node0) = sv;
      #pragma unroll
      for (int r = 0; r < 4; ++r)
        s1[(size_t)(row0 + quad * 4 + r) * H + h] = p1[r] * L2E;
    }
  }
}

// ---------------- Kernel B (j-split, code-prefetched): e -> MFMA -> softmax -> LN -> ELU ----
// 512 blocks x 512 thr. Wave (w: heads {w,w+4}, jh: j-half). Per-lane 64 B of codes
// preloaded as 8 independent uint2 (one latency); s2 staged in LDS; only WhT stays global.
__global__ __launch_bounds__(512, 4) void k_attn(
    const unsigned char* __restrict__ codes,
    const float* __restrict__ s1, const float* __restrict__ s2T,
    const unsigned short* __restrict__ WhT, const float* __restrict__ emb,
    const float* __restrict__ gam, const float* __restrict__ bet,
    float* __restrict__ out)
{
  __shared__ float2 embS[4 * 64];   // [w][et] = (emb[et][w], emb[et][w+4]) * L2E
  __shared__ float2 lnS[16 * 4];    // [i][w] partial (sum, sumsq)
  __shared__ float  s2S[8 * 512];   // [h][j] staged s2 (16 KB)
  __shared__ float  redS[256 * 18]; // [tt][18]: 16 accs + l0 + l1; stride 18 -> 2-way only

  const int t    = threadIdx.x;
  const int b    = blockIdx.x >> 5;
  const int i0   = (blockIdx.x & 31) * 16;
  const int W    = t >> 6;
  const int w    = W & 3;
  const int jh   = W >> 2;
  const int L    = t & 63;
  const int i    = L & 15;
  const int quad = L >> 4;
  const int h0   = w, h1 = w + 4;

  { // stage s2 for all 8 heads (16 KB, coalesced)
    const float4* sg = (const float4*)(s2T + (size_t)b * 8 * 512);
    float4* ss = (float4*)s2S;
    ss[t]       = sg[t];
    ss[t + 512] = sg[t + 512];
  }
  if (t < 256) { // stage emb (pair-packed per head-pair, pre-scaled)
    const int wp = t >> 6, e = t & 63;
    if (e < NE) {
      float2 v; v.x = emb[e * H + wp] * L2E; v.y = emb[e * H + wp + 4] * L2E;
      embS[t] = v;
    }
  }

  const int row   = b * NN + i0 + i;
  const int jbase = jh * 256;

  // ---- preload this lane's entire code strip: 8 x uint2, all in flight at once ----
  uint2 cw[8];
  {
    const unsigned char* cp = codes + (size_t)row * NN + jbase + quad * 8;
    #pragma unroll
    for (int kc = 0; kc < 8; ++kc) cw[kc] = *(const uint2*)(cp + kc * 32);
  }

  const float si0 = s1[(size_t)row * H + h0];
  const float si1 = s1[(size_t)row * H + h1];
  const unsigned short* wt00 = WhT + (size_t)((b * 8 + h0) * 32 + i)      * 512;
  const unsigned short* wt01 = WhT + (size_t)((b * 8 + h0) * 32 + 16 + i) * 512;
  const unsigned short* wt10 = WhT + (size_t)((b * 8 + h1) * 32 + i)      * 512;
  const unsigned short* wt11 = WhT + (size_t)((b * 8 + h1) * 32 + 16 + i) * 512;

  f32x4 acc00 = {0.f,0.f,0.f,0.f}, acc01 = {0.f,0.f,0.f,0.f};
  f32x4 acc10 = {0.f,0.f,0.f,0.f}, acc11 = {0.f,0.f,0.f,0.f};
  float l0 = 0.f, l1 = 0.f;

  __syncthreads();

  #pragma unroll 2
  for (int kc = 0; kc < 8; ++kc) {
    const int ja = jbase + kc * 32 + quad * 8;
    const short8 A00 = *(const short8*)(wt00 + ja);
    const short8 A01 = *(const short8*)(wt01 + ja);
    const short8 A10 = *(const short8*)(wt10 + ja);
    const short8 A11 = *(const short8*)(wt11 + ja);
    const float4 sa0 = *(const float4*)&s2S[h0 * 512 + ja];
    const float4 sb0 = *(const float4*)&s2S[h0 * 512 + ja + 4];
    const float4 sa1 = *(const float4*)&s2S[h1 * 512 + ja];
    const float4 sb1 = *(const float4*)&s2S[h1 * 512 + ja + 4];

    const float s20[8] = {sa0.x, sa0.y, sa0.z, sa0.w, sb0.x, sb0.y, sb0.z, sb0.w};
    const float s21[8] = {sa1.x, sa1.y, sa1.z, sa1.w, sb1.x, sb1.y, sb1.z, sb1.w};

    unsigned u0[8], u1[8];
    #pragma unroll
    for (int q = 0; q < 8; ++q) {
      const unsigned cword = (q < 4) ? cw[kc].x : cw[kc].y;
      const unsigned c = (cword >> ((q & 3) * 8)) & 0x7fu;
      const bool on = c >= 64u;
      const float2 em = embS[w * 64 + (c & 63u)];
      float e0 = si0 + s20[q] + em.x;
      float e1 = si1 + s21[q] + em.y;
      e0 = fmaxf(e0, 0.2f * e0);
      e1 = fmaxf(e1, 0.2f * e1);
      e0 = on ? e0 : MASK;
      e1 = on ? e1 : MASK;
      const float p0 = exp2f(e0);
      const float p1 = exp2f(e1);
      l0 += p0; l1 += p1;
      u0[q] = __float_as_uint(p0) + 0x8000u;
      u1[q] = __float_as_uint(p1) + 0x8000u;
    }
    uint4 U0, U1;
    U0.x = pk_bf16(u0[0], u0[1]); U0.y = pk_bf16(u0[2], u0[3]);
    U0.z = pk_bf16(u0[4], u0[5]); U0.w = pk_bf16(u0[6], u0[7]);
    U1.x = pk_bf16(u1[0], u1[1]); U1.y = pk_bf16(u1[2], u1[3]);
    U1.z = pk_bf16(u1[4], u1[5]); U1.w = pk_bf16(u1[6], u1[7]);
    const short8 B0 = __builtin_bit_cast(short8, U0);
    const short8 B1 = __builtin_bit_cast(short8, U1);

    acc00 = __builtin_amdgcn_mfma_f32_16x16x32_bf16(A00, B0, acc00, 0, 0, 0);
    acc01 = __builtin_amdgcn_mfma_f32_16x16x32_bf16(A01, B0, acc01, 0, 0, 0);
    acc10 = __builtin_amdgcn_mfma_f32_16x16x32_bf16(A10, B1, acc10, 0, 0, 0);
    acc11 = __builtin_amdgcn_mfma_f32_16x16x32_bf16(A11, B1, acc11, 0, 0, 0);
  }

  // intra-wave l reduction: lanes {L, L^16, L^32, L^48} share i
  l0 += __shfl_xor(l0, 16); l0 += __shfl_xor(l0, 32);
  l1 += __shfl_xor(l1, 16); l1 += __shfl_xor(l1, 32);

  // ---- cross-half combine via LDS ----
  const int tt = (w << 6) | L;
  if (jh == 1) {
    float* rp = redS + tt * 18;
    rp[0]=acc00[0]; rp[1]=acc00[1]; rp[2]=acc00[2]; rp[3]=acc00[3];
    rp[4]=acc01[0]; rp[5]=acc01[1]; rp[6]=acc01[2]; rp[7]=acc01[3];
    rp[8]=acc10[0]; rp[9]=acc10[1]; rp[10]=acc10[2]; rp[11]=acc10[3];
    rp[12]=acc11[0]; rp[13]=acc11[1]; rp[14]=acc11[2]; rp[15]=acc11[3];
    rp[16]=l0; rp[17]=l1;
  }
  __syncthreads();

  float vals[16]; float mu, rstd;
  if (jh == 0) {
    const float* rp = redS + tt * 18;
    acc00[0]+=rp[0]; acc00[1]+=rp[1]; acc00[2]+=rp[2]; acc00[3]+=rp[3];
    acc01[0]+=rp[4]; acc01[1]+=rp[5]; acc01[2]+=rp[6]; acc01[3]+=rp[7];
    acc10[0]+=rp[8]; acc10[1]+=rp[9]; acc10[2]+=rp[10]; acc10[3]+=rp[11];
    acc11[0]+=rp[12]; acc11[1]+=rp[13]; acc11[2]+=rp[14]; acc11[3]+=rp[15];
    l0 += rp[16]; l1 += rp[17];
    const float inv0 = __builtin_amdgcn_rcpf(l0);
    const float inv1 = __builtin_amdgcn_rcpf(l1);
    #pragma unroll
    for (int r = 0; r < 4; ++r) {
      vals[r]      = acc00[r] * inv0;
      vals[4 + r]  = acc01[r] * inv0;
      vals[8 + r]  = acc10[r] * inv1;
      vals[12 + r] = acc11[r] * inv1;
    }
    float s = 0.f, ss = 0.f;
    #pragma unroll
    for (int k = 0; k < 16; ++k) { s += vals[k]; ss += vals[k] * vals[k]; }
    s += __shfl_xor(s, 16); ss += __shfl_xor(ss, 16);
    s += __shfl_xor(s, 32); ss += __shfl_xor(ss, 32);
    if (quad == 0) { float2 v; v.x = s; v.y = ss; lnS[i * 4 + w] = v; }
  }
  __syncthreads();
  if (jh == 1) return;

  {
    float S = 0.f, SS = 0.f;
    #pragma unroll
    for (int ww = 0; ww < 4; ++ww) { const float2 v = lnS[i * 4 + ww]; S += v.x; SS += v.y; }
    mu = S * (1.0f / 256.0f);
    const float var = SS * (1.0f / 256.0f) - mu * mu;
    rstd = rsqrtf(var + 1e-5f);
  }

  const int fb[4] = { h0 * 32 + quad * 4, h0 * 32 + 16 + quad * 4,
                      h1 * 32 + quad * 4, h1 * 32 + 16 + quad * 4 };
  #pragma unroll
  for (int g = 0; g < 4; ++g) {
    const float4 gv = *(const float4*)(gam + fb[g]);
    const float4 bv = *(const float4*)(bet + fb[g]);
    float4 o;
    o.x = (vals[g*4+0] - mu) * rstd * gv.x + bv.x;
    o.y = (vals[g*4+1] - mu) * rstd * gv.y + bv.y;
    o.z = (vals[g*4+2] - mu) * rstd * gv.z + bv.z;
    o.w = (vals[g*4+3] - mu) * rstd * gv.w + bv.w;
    o.x = o.x > 0.f ? o.x : exp2f(o.x * L2E) - 1.f;
    o.y = o.y > 0.f ? o.y : exp2f(o.y * L2E) - 1.f;
    o.z = o.z > 0.f ? o.z : exp2f(o.z * L2E) - 1.f;
    o.w = o.w > 0.f ? o.w : exp2f(o.w * L2E) - 1.f;
    *(float4*)(out + (size_t)row * FOUT + fb[g]) = o;
  }
}

extern "C" void kernel_launch(void* const* d_in, const int* in_sizes, int n_in,
                              void* d_out, int out_size, void* d_ws, size_t ws_size,
                              hipStream_t stream) {
  (void)in_sizes; (void)n_in; (void)out_size; (void)ws_size;
  const float* x   = (const float*)d_in[0];
  const int*   adj = (const int*)  d_in[1];
  const int*   ety = (const int*)  d_in[2];
  const float* Wm  = (const float*)d_in[3];
  const float* a1  = (const float*)d_in[4];
  const float* a2  = (const float*)d_in[5];
  const float* emb = (const float*)d_in[6];
  const float* gam = (const float*)d_in[7];
  const float* bet = (const float*)d_in[8];
  float* out = (float*)d_out;

  unsigned short* WhT = (unsigned short*)d_ws;              // 16*8*32*512 bf16 = 4 MB
  unsigned short* WbT = WhT + (size_t)NB * H * 32 * 512;    // 256*256 bf16 = 128 KB
  float* s1   = (float*)(WbT + (size_t)FOUT * FIN);         // 8192*8 fp32 (pre-scaled)
  float* s2T  = s1 + (size_t)NB * NN * H;                   // 16*8*512 fp32 (pre-scaled)
  unsigned char* codes = (unsigned char*)(s2T + (size_t)NB * H * NN); // 16*512*512 = 4.2 MB

  k_prep<<<dim3(FIN),  dim3(256), 0, stream>>>(Wm, WbT);
  k_pack<<<dim3(NB * NN * NN / (256 * 16)), dim3(256), 0, stream>>>(adj, ety, (unsigned*)codes);
  k_gemm<<<dim3(NB * NN / 16), dim3(512), 0, stream>>>(x, WbT, a1, a2, WhT, s1, s2T);
  k_attn<<<dim3(NB * (NN / 16)), dim3(512), 0, stream>>>(codes, s1, s2T, WhT, emb, gam, bet, out);
}

// Round 6
// 136.790 us; speedup vs baseline: 1.3926x; 1.0131x over previous
//
#include <hip/hip_runtime.h>
#include <hip/hip_bf16.h>
#include <stdint.h>

namespace gat {
constexpr int NB   = 16;
constexpr int NN   = 512;
constexpr int FIN  = 256;
constexpr int FOUT = 256;
constexpr int H    = 8;
constexpr int NE   = 50;
constexpr float L2E  = 1.4426950408889634f;   // log2(e); s1,s2,emb pre-scaled so exp(e)=exp2(e')
constexpr float MASK = -115.41500f;           // -80 * log2e; exp2 -> 2.4e-35 (normal fp32)
}
using namespace gat;

typedef __attribute__((ext_vector_type(8))) short short8;  // 8 bf16 = 4 VGPRs (MFMA A/B frag)
typedef __attribute__((ext_vector_type(4))) float f32x4;   // MFMA C/D frag

__device__ __forceinline__ unsigned pk_bf16(unsigned ulo, unsigned uhi) {
  return __builtin_amdgcn_perm(uhi, ulo, 0x07060302u);
}
__device__ __forceinline__ unsigned pk2f(float a, float b) {
  return pk_bf16(__float_as_uint(a) + 0x8000u, __float_as_uint(b) + 0x8000u);
}
__device__ __forceinline__ unsigned short bf1(float a) {
  return (unsigned short)((__float_as_uint(a) + 0x8000u) >> 16);
}

// ---------------- Kernel PRE (fused): codes pack + WbTa transpose + v1/v2 ----------------
// blocks 0..1023: codes = adj<<6 | ety (1 B/edge).  blocks 1024..1279: WbTa[f][k]=bf16(W[k][f]).
// block 1280: aug rows 256..271 of WbTa = v1/v2 (s1/s2 become 16 extra GEMM columns).
__global__ __launch_bounds__(256) void k_pre(const int* __restrict__ adj,
                                             const int* __restrict__ ety,
                                             const float* __restrict__ Wm,
                                             const float* __restrict__ a1,
                                             const float* __restrict__ a2,
                                             unsigned* __restrict__ codes,
                                             unsigned short* __restrict__ WbTa) {
  const int blk = blockIdx.x;
  if (blk < 1024) {
    const size_t base = ((size_t)blk * 256 + threadIdx.x) * 16;
    const int4* ap = (const int4*)(adj + base);
    const int4* ep = (const int4*)(ety + base);
    unsigned o[4];
    #pragma unroll
    for (int g = 0; g < 4; ++g) {
      const int4 a = ap[g];
      const int4 e = ep[g];
      o[g] = (unsigned)(e.x | (a.x << 6))
           | ((unsigned)(e.y | (a.y << 6)) << 8)
           | ((unsigned)(e.z | (a.z << 6)) << 16)
           | ((unsigned)(e.w | (a.w << 6)) << 24);
    }
    uint4 v; v.x = o[0]; v.y = o[1]; v.z = o[2]; v.w = o[3];
    *(uint4*)(codes + base / 4) = v;
  } else if (blk < 1280) {
    const int k = blk - 1024;
    const int f = threadIdx.x;
    WbTa[f * FIN + k] = bf1(Wm[k * FOUT + f]);
  } else {
    const int k = threadIdx.x;
    const float* wr = Wm + (size_t)k * FOUT;
    #pragma unroll
    for (int h = 0; h < H; ++h) {
      float v1 = 0.f, v2 = 0.f;
      #pragma unroll
      for (int d = 0; d < 32; ++d) {
        const float wv = wr[h * 32 + d];
        v1 += wv * a1[d];
        v2 += wv * a2[d];
      }
      WbTa[(256 + h) * FIN + k] = bf1(v1);   // s1 aug col
      WbTa[(264 + h) * FIN + k] = bf1(v2);   // s2 aug col
    }
  }
}

// ---------------- Kernel A (MFMA): [Wh | s1 | s2] = x @ [W | v1 | v2] ----------------
// 512 blocks x 256 thr (4 waves). Wave w owns f-slice [w*64, w*64+64); wave 3 also the
// 16 aug columns. NO shuffle epilogue: s1/s2 come out of the MFMA D-fragments directly.
__global__ __launch_bounds__(256, 4) void k_gemm(
    const float* __restrict__ x, const unsigned short* __restrict__ WbTa,
    unsigned short* __restrict__ WhT, float* __restrict__ s1T, float* __restrict__ s2T)
{
  __shared__ alignas(16) unsigned short xS[16 * 264];  // row stride 264 -> 2-way only
  const int t    = threadIdx.x;
  const int row0 = blockIdx.x * 16;

  { // stage 16 rows of x, fp32 -> bf16 (256 threads, 16 k's each)
    const int r  = t >> 4;
    const int kb = (t & 15) * 16;
    const float4* xg = (const float4*)(x + (size_t)(row0 + r) * FIN + kb);
    const float4 v0 = xg[0], v1 = xg[1], v2 = xg[2], v3 = xg[3];
    uint4 o0, o1;
    o0.x = pk2f(v0.x, v0.y); o0.y = pk2f(v0.z, v0.w);
    o0.z = pk2f(v1.x, v1.y); o0.w = pk2f(v1.z, v1.w);
    o1.x = pk2f(v2.x, v2.y); o1.y = pk2f(v2.z, v2.w);
    o1.z = pk2f(v3.x, v3.y); o1.w = pk2f(v3.z, v3.w);
    *(uint4*)&xS[r * 264 + kb]     = o0;
    *(uint4*)&xS[r * 264 + kb + 8] = o1;
  }
  __syncthreads();

  const int w    = t >> 6;
  const int L    = t & 63;
  const int nn   = L & 15;     // A: node row m; B: col n within tile
  const int quad = L >> 4;     // k sub-chunk; D: row group
  const unsigned short* wb = WbTa + (size_t)(w * 64 + nn) * FIN + quad * 8;
  const unsigned short* wa = WbTa + (size_t)(256 + nn) * FIN + quad * 8;   // aug tile
  const unsigned short* xp = &xS[nn * 264 + quad * 8];

  f32x4 acc0 = {0.f,0.f,0.f,0.f}, acc1 = {0.f,0.f,0.f,0.f};
  f32x4 acc2 = {0.f,0.f,0.f,0.f}, acc3 = {0.f,0.f,0.f,0.f};
  f32x4 accA = {0.f,0.f,0.f,0.f};

  #pragma unroll
  for (int kc = 0; kc < 8; ++kc) {
    const int k0 = kc * 32;
    const short8 A  = *(const short8*)(xp + k0);
    const short8 B0 = *(const short8*)(wb + k0);
    const short8 B1 = *(const short8*)(wb + 16 * FIN + k0);
    const short8 B2 = *(const short8*)(wb + 32 * FIN + k0);
    const short8 B3 = *(const short8*)(wb + 48 * FIN + k0);
    acc0 = __builtin_amdgcn_mfma_f32_16x16x32_bf16(A, B0, acc0, 0, 0, 0);
    acc1 = __builtin_amdgcn_mfma_f32_16x16x32_bf16(A, B1, acc1, 0, 0, 0);
    acc2 = __builtin_amdgcn_mfma_f32_16x16x32_bf16(A, B2, acc2, 0, 0, 0);
    acc3 = __builtin_amdgcn_mfma_f32_16x16x32_bf16(A, B3, acc3, 0, 0, 0);
    if (w == 3) {
      const short8 BA = *(const short8*)(wa + k0);
      accA = __builtin_amdgcn_mfma_f32_16x16x32_bf16(A, BA, accA, 0, 0, 0);
    }
  }

  // D layout: lane holds col n = tile*16 + nn, rows (nodes) = quad*4 + r
  const int b     = row0 >> 9;
  const int node0 = (row0 & 511) + quad * 4;
  f32x4 accs[4] = {acc0, acc1, acc2, acc3};

  #pragma unroll
  for (int ft = 0; ft < 4; ++ft) {
    const int f = w * 64 + ft * 16 + nn;
    uint2 o;
    o.x = pk2f(accs[ft][0], accs[ft][1]);
    o.y = pk2f(accs[ft][2], accs[ft][3]);
    *(uint2*)(WhT + (size_t)((b * 8 + (f >> 5)) * 32 + (f & 31)) * 512 + node0) = o;
  }

  if (w == 3) {  // aug cols: n<8 -> s1 head n; n>=8 -> s2 head n-8 (pre-scaled by log2e)
    float4 sv;
    sv.x = accA[0] * L2E; sv.y = accA[1] * L2E;
    sv.z = accA[2] * L2E; sv.w = accA[3] * L2E;
    float* dst = (nn < 8) ? (s1T + (size_t)(b * 8 + nn) * 512 + node0)
                          : (s2T + (size_t)(b * 8 + (nn - 8)) * 512 + node0);
    *(float4*)dst = sv;
  }
}

// ---------------- Kernel B (j-split, code-prefetched, A-pipelined) ----------------
// 512 blocks x 512 thr. Wave (w: heads {w,w+4}, jh: j-half). Codes preloaded 8-deep in
// registers; s2 in LDS; A-frags (WhT) software-pipelined 1 iteration ahead.
__global__ __launch_bounds__(512, 4) void k_attn(
    const unsigned char* __restrict__ codes,
    const float* __restrict__ s1T, const float* __restrict__ s2T,
    const unsigned short* __restrict__ WhT, const float* __restrict__ emb,
    const float* __restrict__ gam, const float* __restrict__ bet,
    float* __restrict__ out)
{
  __shared__ float2 embS[4 * 64];   // [w][et] = (emb[et][w], emb[et][w+4]) * L2E
  __shared__ float2 lnS[16 * 4];    // [i][w] partial (sum, sumsq)
  __shared__ float  s2S[8 * 512];   // [h][j] staged s2 (16 KB)
  __shared__ float  redS[256 * 18]; // [tt][18]: 16 accs + l0 + l1; stride 18 -> 2-way only

  const int t    = threadIdx.x;
  const int b    = blockIdx.x >> 5;
  const int i0   = (blockIdx.x & 31) * 16;
  const int W    = t >> 6;
  const int w    = W & 3;
  const int jh   = W >> 2;
  const int L    = t & 63;
  const int i    = L & 15;
  const int quad = L >> 4;
  const int h0   = w, h1 = w + 4;

  { // stage s2 for all 8 heads (16 KB, coalesced)
    const float4* sg = (const float4*)(s2T + (size_t)b * 8 * 512);
    float4* ss = (float4*)s2S;
    ss[t]       = sg[t];
    ss[t + 512] = sg[t + 512];
  }
  if (t < 256) { // stage emb (pair-packed per head-pair, pre-scaled)
    const int wp = t >> 6, e = t & 63;
    if (e < NE) {
      float2 v; v.x = emb[e * H + wp] * L2E; v.y = emb[e * H + wp + 4] * L2E;
      embS[t] = v;
    }
  }

  const int row   = b * NN + i0 + i;
  const int jbase = jh * 256;

  // ---- preload this lane's entire code strip: 8 x uint2, all in flight at once ----
  uint2 cw[8];
  {
    const unsigned char* cp = codes + (size_t)row * NN + jbase + quad * 8;
    #pragma unroll
    for (int kc = 0; kc < 8; ++kc) cw[kc] = *(const uint2*)(cp + kc * 32);
  }

  const float si0 = s1T[(size_t)(b * 8 + h0) * 512 + i0 + i];
  const float si1 = s1T[(size_t)(b * 8 + h1) * 512 + i0 + i];
  const unsigned short* wt00 = WhT + (size_t)((b * 8 + h0) * 32 + i)      * 512;
  const unsigned short* wt01 = WhT + (size_t)((b * 8 + h0) * 32 + 16 + i) * 512;
  const unsigned short* wt10 = WhT + (size_t)((b * 8 + h1) * 32 + i)      * 512;
  const unsigned short* wt11 = WhT + (size_t)((b * 8 + h1) * 32 + 16 + i) * 512;

  f32x4 acc00 = {0.f,0.f,0.f,0.f}, acc01 = {0.f,0.f,0.f,0.f};
  f32x4 acc10 = {0.f,0.f,0.f,0.f}, acc11 = {0.f,0.f,0.f,0.f};
  float l0 = 0.f, l1 = 0.f;

  // A-frag pipeline: issue kc=0 loads now
  const int ja0 = jbase + quad * 8;
  short8 nA00 = *(const short8*)(wt00 + ja0);
  short8 nA01 = *(const short8*)(wt01 + ja0);
  short8 nA10 = *(const short8*)(wt10 + ja0);
  short8 nA11 = *(const short8*)(wt11 + ja0);

  __syncthreads();

  #pragma unroll
  for (int kc = 0; kc < 8; ++kc) {
    const int ja  = jbase + kc * 32 + quad * 8;
    const short8 A00 = nA00, A01 = nA01, A10 = nA10, A11 = nA11;
    { // prefetch next iteration's A-frags (last iter: +32 stays inside d_ws)
      const int jn = ja + 32;
      nA00 = *(const short8*)(wt00 + jn);
      nA01 = *(const short8*)(wt01 + jn);
      nA10 = *(const short8*)(wt10 + jn);
      nA11 = *(const short8*)(wt11 + jn);
    }
    const float4 sa0 = *(const float4*)&s2S[h0 * 512 + ja];
    const float4 sb0 = *(const float4*)&s2S[h0 * 512 + ja + 4];
    const float4 sa1 = *(const float4*)&s2S[h1 * 512 + ja];
    const float4 sb1 = *(const float4*)&s2S[h1 * 512 + ja + 4];

    const float s20[8] = {sa0.x, sa0.y, sa0.z, sa0.w, sb0.x, sb0.y, sb0.z, sb0.w};
    const float s21[8] = {sa1.x, sa1.y, sa1.z, sa1.w, sb1.x, sb1.y, sb1.z, sb1.w};

    unsigned u0[8], u1[8];
    #pragma unroll
    for (int q = 0; q < 8; ++q) {
      const unsigned cword = (q < 4) ? cw[kc].x : cw[kc].y;
      const unsigned c = (cword >> ((q & 3) * 8)) & 0x7fu;
      const bool on = c >= 64u;
      const float2 em = embS[w * 64 + (c & 63u)];
      float e0 = si0 + s20[q] + em.x;
      float e1 = si1 + s21[q] + em.y;
      e0 = fmaxf(e0, 0.2f * e0);
      e1 = fmaxf(e1, 0.2f * e1);
      e0 = on ? e0 : MASK;
      e1 = on ? e1 : MASK;
      const float p0 = exp2f(e0);
      const float p1 = exp2f(e1);
      l0 += p0; l1 += p1;
      u0[q] = __float_as_uint(p0) + 0x8000u;
      u1[q] = __float_as_uint(p1) + 0x8000u;
    }
    uint4 U0, U1;
    U0.x = pk_bf16(u0[0], u0[1]); U0.y = pk_bf16(u0[2], u0[3]);
    U0.z = pk_bf16(u0[4], u0[5]); U0.w = pk_bf16(u0[6], u0[7]);
    U1.x = pk_bf16(u1[0], u1[1]); U1.y = pk_bf16(u1[2], u1[3]);
    U1.z = pk_bf16(u1[4], u1[5]); U1.w = pk_bf16(u1[6], u1[7]);
    const short8 B0 = __builtin_bit_cast(short8, U0);
    const short8 B1 = __builtin_bit_cast(short8, U1);

    acc00 = __builtin_amdgcn_mfma_f32_16x16x32_bf16(A00, B0, acc00, 0, 0, 0);
    acc01 = __builtin_amdgcn_mfma_f32_16x16x32_bf16(A01, B0, acc01, 0, 0, 0);
    acc10 = __builtin_amdgcn_mfma_f32_16x16x32_bf16(A10, B1, acc10, 0, 0, 0);
    acc11 = __builtin_amdgcn_mfma_f32_16x16x32_bf16(A11, B1, acc11, 0, 0, 0);
  }

  // intra-wave l reduction: lanes {L, L^16, L^32, L^48} share i
  l0 += __shfl_xor(l0, 16); l0 += __shfl_xor(l0, 32);
  l1 += __shfl_xor(l1, 16); l1 += __shfl_xor(l1, 32);

  // ---- cross-half combine via LDS ----
  const int tt = (w << 6) | L;
  if (jh == 1) {
    float* rp = redS + tt * 18;
    rp[0]=acc00[0]; rp[1]=acc00[1]; rp[2]=acc00[2]; rp[3]=acc00[3];
    rp[4]=acc01[0]; rp[5]=acc01[1]; rp[6]=acc01[2]; rp[7]=acc01[3];
    rp[8]=acc10[0]; rp[9]=acc10[1]; rp[10]=acc10[2]; rp[11]=acc10[3];
    rp[12]=acc11[0]; rp[13]=acc11[1]; rp[14]=acc11[2]; rp[15]=acc11[3];
    rp[16]=l0; rp[17]=l1;
  }
  __syncthreads();

  float vals[16]; float mu, rstd;
  if (jh == 0) {
    const float* rp = redS + tt * 18;
    acc00[0]+=rp[0]; acc00[1]+=rp[1]; acc00[2]+=rp[2]; acc00[3]+=rp[3];
    acc01[0]+=rp[4]; acc01[1]+=rp[5]; acc01[2]+=rp[6]; acc01[3]+=rp[7];
    acc10[0]+=rp[8]; acc10[1]+=rp[9]; acc10[2]+=rp[10]; acc10[3]+=rp[11];
    acc11[0]+=rp[12]; acc11[1]+=rp[13]; acc11[2]+=rp[14]; acc11[3]+=rp[15];
    l0 += rp[16]; l1 += rp[17];
    const float inv0 = __builtin_amdgcn_rcpf(l0);
    const float inv1 = __builtin_amdgcn_rcpf(l1);
    #pragma unroll
    for (int r = 0; r < 4; ++r) {
      vals[r]      = acc00[r] * inv0;
      vals[4 + r]  = acc01[r] * inv0;
      vals[8 + r]  = acc10[r] * inv1;
      vals[12 + r] = acc11[r] * inv1;
    }
    float s = 0.f, ss = 0.f;
    #pragma unroll
    for (int k = 0; k < 16; ++k) { s += vals[k]; ss += vals[k] * vals[k]; }
    s += __shfl_xor(s, 16); ss += __shfl_xor(ss, 16);
    s += __shfl_xor(s, 32); ss += __shfl_xor(ss, 32);
    if (quad == 0) { float2 v; v.x = s; v.y = ss; lnS[i * 4 + w] = v; }
  }
  __syncthreads();
  if (jh == 1) return;

  {
    float S = 0.f, SS = 0.f;
    #pragma unroll
    for (int ww = 0; ww < 4; ++ww) { const float2 v = lnS[i * 4 + ww]; S += v.x; SS += v.y; }
    mu = S * (1.0f / 256.0f);
    const float var = SS * (1.0f / 256.0f) - mu * mu;
    rstd = rsqrtf(var + 1e-5f);
  }

  const int fb[4] = { h0 * 32 + quad * 4, h0 * 32 + 16 + quad * 4,
                      h1 * 32 + quad * 4, h1 * 32 + 16 + quad * 4 };
  #pragma unroll
  for (int g = 0; g < 4; ++g) {
    const float4 gv = *(const float4*)(gam + fb[g]);
    const float4 bv = *(const float4*)(bet + fb[g]);
    float4 o;
    o.x = (vals[g*4+0] - mu) * rstd * gv.x + bv.x;
    o.y = (vals[g*4+1] - mu) * rstd * gv.y + bv.y;
    o.z = (vals[g*4+2] - mu) * rstd * gv.z + bv.z;
    o.w = (vals[g*4+3] - mu) * rstd * gv.w + bv.w;
    o.x = o.x > 0.f ? o.x : exp2f(o.x * L2E) - 1.f;
    o.y = o.y > 0.f ? o.y : exp2f(o.y * L2E) - 1.f;
    o.z = o.z > 0.f ? o.z : exp2f(o.z * L2E) - 1.f;
    o.w = o.w > 0.f ? o.w : exp2f(o.w * L2E) - 1.f;
    *(float4*)(out + (size_t)row * FOUT + fb[g]) = o;
  }
}

extern "C" void kernel_launch(void* const* d_in, const int* in_sizes, int n_in,
                              void* d_out, int out_size, void* d_ws, size_t ws_size,
                              hipStream_t stream) {
  (void)in_sizes; (void)n_in; (void)out_size; (void)ws_size;
  const float* x   = (const float*)d_in[0];
  const int*   adj = (const int*)  d_in[1];
  const int*   ety = (const int*)  d_in[2];
  const float* Wm  = (const float*)d_in[3];
  const float* a1  = (const float*)d_in[4];
  const float* a2  = (const float*)d_in[5];
  const float* emb = (const float*)d_in[6];
  const float* gam = (const float*)d_in[7];
  const float* bet = (const float*)d_in[8];
  float* out = (float*)d_out;

  unsigned short* WhT  = (unsigned short*)d_ws;             // 16*8*32*512 bf16 = 4 MB
  unsigned short* WbTa = WhT + (size_t)NB * H * 32 * 512;   // 272*256 bf16 = 139264 elems
  float* s1T  = (float*)(WbTa + (size_t)272 * FIN);         // 16*8*512 fp32 (pre-scaled)
  float* s2T  = s1T + (size_t)NB * H * NN;                  // 16*8*512 fp32 (pre-scaled)
  unsigned char* codes = (unsigned char*)(s2T + (size_t)NB * H * NN); // 4.2 MB

  k_pre<<<dim3(1281), dim3(256), 0, stream>>>(adj, ety, Wm, a1, a2, (unsigned*)codes, WbTa);
  k_gemm<<<dim3(NB * NN / 16), dim3(256), 0, stream>>>(x, WbTa, WhT, s1T, s2T);
  k_attn<<<dim3(NB * (NN / 16)), dim3(512), 0, stream>>>(codes, s1T, s2T, WhT, emb, gam, bet, out);
}